// Round 2
// baseline (1057.059 us; speedup 1.0000x reference)
//
#include <hip/hip_runtime.h>

// Problem constants: B=4, S=2048, D=1024
#define BB 4
#define SS 2048
#define DD 1024
#define MM (BB * SS)          // 8192 rows total
#define MH (MM / 2)           // 4096 rows per half (two-half pipeline keeps ws at ~34 MB)
#define PI_F 3.14159265358979323846f

// ---------------------------------------------------------------------------
// FFT helpers: N=1024, 256 threads/block, data in LDS (re[1024], im[1024]).
// Forward = DIF (natural in -> bit-reversed out). Inverse = DIT with conj
// twiddles (bit-reversed in -> natural out). All pointwise ops between the
// forward and inverse transforms are per-bin, so bit-reversed bin order is
// used throughout the middle of the pipeline (no bit-reversal passes).
// ---------------------------------------------------------------------------

__device__ __forceinline__ void fft_dif_fwd(float* re, float* im,
                                            const float* twc, const float* tws,
                                            int t) {
  #pragma unroll
  for (int s = 10; s >= 1; --s) {
    const int half = 1 << (s - 1);
    #pragma unroll
    for (int r = 0; r < 2; ++r) {
      const int j   = t + (r << 8);         // butterfly id 0..511
      const int pos = j & (half - 1);
      const int grp = j >> (s - 1);
      const int i1  = (grp << s) + pos;
      const int i2  = i1 + half;
      const int wi  = pos << (10 - s);
      const float c  = twc[wi];
      const float sn = tws[wi];
      const float ur = re[i1], ui = im[i1];
      const float xr = re[i2], xi = im[i2];
      const float dr = ur - xr, di = ui - xi;
      re[i1] = ur + xr;
      im[i1] = ui + xi;
      re[i2] = dr * c - di * sn;
      im[i2] = dr * sn + di * c;
    }
    __syncthreads();
  }
}

__device__ __forceinline__ void fft_dit_inv(float* re, float* im,
                                            const float* twc, const float* tws,
                                            int t) {
  #pragma unroll
  for (int s = 1; s <= 10; ++s) {
    const int half = 1 << (s - 1);
    #pragma unroll
    for (int r = 0; r < 2; ++r) {
      const int j   = t + (r << 8);
      const int pos = j & (half - 1);
      const int grp = j >> (s - 1);
      const int i1  = (grp << s) + pos;
      const int i2  = i1 + half;
      const int wi  = pos << (10 - s);
      const float c  = twc[wi];
      const float sn = -tws[wi];            // conj for inverse
      const float xr = re[i2], xi = im[i2];
      const float tr = xr * c - xi * sn;
      const float ti = xr * sn + xi * c;
      const float ur = re[i1], ui = im[i1];
      re[i1] = ur + tr;
      im[i1] = ui + ti;
      re[i2] = ur - tr;
      im[i2] = ui - ti;
    }
    __syncthreads();
  }
}

__device__ __forceinline__ void fill_twiddles(float* twc, float* tws, int t) {
  #pragma unroll
  for (int i = t; i < 512; i += 256) {
    float a = -2.0f * PI_F * (float)i / 1024.0f;
    float s, c;
    sincosf(a, &s, &c);
    twc[i] = c;
    tws[i] = s;
  }
}

// ---------------------------------------------------------------------------
// GEMM: C[m][n] = sum_k A[m][k] * W[n][k]   (x @ W^T, row-major, NT form)
// 64x64 tile, TK=16, 256 threads, 4x4 outputs/thread.
// blockIdx.z selects W0/W1 and a DD-float column offset into C (used to
// produce the interleaved KV layout [row][2][1024] with ldc=2048).
// ---------------------------------------------------------------------------
__global__ __launch_bounds__(256) void gemm_nt(
    const float* __restrict__ A,
    const float* __restrict__ W0, const float* __restrict__ W1,
    float* __restrict__ C, long ldc) {
  const float* Wm = (blockIdx.z == 0) ? W0 : W1;
  float* Cm = C + (long)blockIdx.z * DD;

  __shared__ float As[16][64];  // [k][m]
  __shared__ float Bs[16][64];  // [k][n]

  const int tx = threadIdx.x;   // 0..15
  const int ty = threadIdx.y;   // 0..15
  const int tid = ty * 16 + tx; // 0..255
  const int lr = tid >> 2;            // 0..63: tile row
  const int lk = (tid & 3) * 4;       // 0,4,8,12: k-chunk

  const long rowA = (long)blockIdx.x * 64 + lr;
  const long rowB = (long)blockIdx.y * 64 + lr;

  float acc[4][4] = {};

  for (int k0 = 0; k0 < DD; k0 += 16) {
    const float4 av = *(const float4*)&A [rowA * DD + k0 + lk];
    const float4 bv = *(const float4*)&Wm[rowB * DD + k0 + lk];
    __syncthreads();  // previous tile fully consumed
    As[lk + 0][lr] = av.x; As[lk + 1][lr] = av.y;
    As[lk + 2][lr] = av.z; As[lk + 3][lr] = av.w;
    Bs[lk + 0][lr] = bv.x; Bs[lk + 1][lr] = bv.y;
    Bs[lk + 2][lr] = bv.z; Bs[lk + 3][lr] = bv.w;
    __syncthreads();
    #pragma unroll
    for (int kk = 0; kk < 16; ++kk) {
      float a[4], b[4];
      #pragma unroll
      for (int i = 0; i < 4; ++i) a[i] = As[kk][ty * 4 + i];
      #pragma unroll
      for (int j = 0; j < 4; ++j) b[j] = Bs[kk][tx * 4 + j];
      #pragma unroll
      for (int i = 0; i < 4; ++i)
        #pragma unroll
        for (int j = 0; j < 4; ++j) acc[i][j] += a[i] * b[j];
    }
  }

  const long m0 = (long)blockIdx.x * 64 + ty * 4;
  const long n0 = (long)blockIdx.y * 64 + tx * 4;
  #pragma unroll
  for (int i = 0; i < 4; ++i) {
    float4 o = make_float4(acc[i][0], acc[i][1], acc[i][2], acc[i][3]);
    *(float4*)&Cm[(m0 + i) * ldc + n0] = o;
  }
}

// ---------------------------------------------------------------------------
// Bind (in place): KV row = [k(1024) | v(1024)] floats. Reads both into
// LDS/registers, then overwrites the SAME 8 KB region with
// P = FFT(k)*FFT(v) as float2[1024] (bit-reversed bins).
// Per-block in-place: block m only touches row m -> cross-block safe.
// ---------------------------------------------------------------------------
__global__ __launch_bounds__(256) void bind_kernel(float* __restrict__ KV) {
  __shared__ float re[1024], im[1024];
  __shared__ float twc[512], tws[512];
  const int t = threadIdx.x;
  float* row = KV + (long)blockIdx.x * 2048;

  fill_twiddles(twc, tws, t);
  #pragma unroll
  for (int m = 0; m < 4; ++m) {
    const int i = t + 256 * m;
    re[i] = row[i];           // k
    im[i] = 0.0f;
  }
  __syncthreads();
  fft_dif_fwd(re, im, twc, tws, t);

  float fkr[4], fki[4];
  #pragma unroll
  for (int m = 0; m < 4; ++m) {
    const int i = t + 256 * m;
    fkr[m] = re[i];
    fki[m] = im[i];
  }
  __syncthreads();
  #pragma unroll
  for (int m = 0; m < 4; ++m) {
    const int i = t + 256 * m;
    re[i] = row[1024 + i];    // v
    im[i] = 0.0f;
  }
  __syncthreads();
  fft_dif_fwd(re, im, twc, tws, t);

  float2* P = (float2*)row;   // in-place overwrite; all reads of row are done
  #pragma unroll
  for (int m = 0; m < 4; ++m) {
    const int i = t + 256 * m;
    const float vr = re[i], vi = im[i];
    P[i] = make_float2(fkr[m] * vr - fki[m] * vi,
                       fkr[m] * vi + fki[m] * vr);
  }
}

// ---------------------------------------------------------------------------
// Causal cumsum over s per (b, bin), for a 2-batch half: chunked 3-pass scan.
// S=2048 -> 32 chunks of 64. csum layout: [b2*32+chunk][bin] float2.
// ---------------------------------------------------------------------------
__global__ __launch_bounds__(1024) void scan_chunk_sum(
    const float2* __restrict__ P, float2* __restrict__ csum) {
  const int b2 = blockIdx.x >> 5;     // 0..1
  const int chunk = blockIdx.x & 31;
  const int f = threadIdx.x;          // bin 0..1023
  long base = ((long)b2 * SS + (long)chunk * 64) * DD + f;
  float sr = 0.0f, si = 0.0f;
  for (int i = 0; i < 64; ++i) {
    float2 p = P[base + (long)i * DD];
    sr += p.x; si += p.y;
  }
  csum[(long)blockIdx.x * DD + f] = make_float2(sr, si);
}

__global__ __launch_bounds__(1024) void scan_chunk_scan(float2* csum) {
  const int b2 = blockIdx.x;          // 0..1
  const int f = threadIdx.x;
  float rr = 0.0f, ri = 0.0f;
  for (int c = 0; c < 32; ++c) {
    const long o = ((long)b2 * 32 + c) * DD + f;
    float2 v = csum[o];
    csum[o] = make_float2(rr, ri);    // exclusive scan of chunk sums
    rr += v.x; ri += v.y;
  }
}

__global__ __launch_bounds__(1024) void scan_apply(
    float2* __restrict__ P, const float2* __restrict__ csum) {
  const int b2 = blockIdx.x >> 5;
  const int chunk = blockIdx.x & 31;
  const int f = threadIdx.x;
  float2 off = csum[(long)blockIdx.x * DD + f];
  float ar = off.x, ai = off.y;
  long base = ((long)b2 * SS + (long)chunk * 64) * DD + f;
  for (int i = 0; i < 64; ++i) {
    const long o = base + (long)i * DD;
    float2 p = P[o];
    ar += p.x; ai += p.y;
    P[o] = make_float2(ar, ai);       // inclusive cumsum
  }
}

// ---------------------------------------------------------------------------
// Unbind (in place on d_out): row holds q (written by gemm_q). Read q fully
// into LDS, fq = FFT(q); z = mem * conj(fq); out_row = Re(IFFT(z)) written
// back over the same row. Per-block in-place -> cross-block safe.
// ---------------------------------------------------------------------------
__global__ __launch_bounds__(256) void unbind_kernel(
    float* __restrict__ qout, const float2* __restrict__ mem) {
  __shared__ float re[1024], im[1024];
  __shared__ float twc[512], tws[512];
  const int t = threadIdx.x;
  float* row = qout + (long)blockIdx.x * DD;
  const float2* mrow = mem + (long)blockIdx.x * DD;

  fill_twiddles(twc, tws, t);
  #pragma unroll
  for (int m = 0; m < 4; ++m) {
    const int i = t + 256 * m;
    re[i] = row[i];
    im[i] = 0.0f;
  }
  __syncthreads();
  fft_dif_fwd(re, im, twc, tws, t);

  float zr[4], zi[4];
  #pragma unroll
  for (int m = 0; m < 4; ++m) {
    const int i = t + 256 * m;
    const float fr = re[i], fi = im[i];
    const float2 mv = mrow[i];
    zr[m] = mv.x * fr + mv.y * fi;    // mem * conj(fq)
    zi[m] = mv.y * fr - mv.x * fi;
  }
  __syncthreads();
  #pragma unroll
  for (int m = 0; m < 4; ++m) {
    const int i = t + 256 * m;
    re[i] = zr[m];
    im[i] = zi[m];
  }
  __syncthreads();
  fft_dit_inv(re, im, twc, tws, t);

  const float scale = 1.0f / 1024.0f;
  #pragma unroll
  for (int m = 0; m < 4; ++m) {
    const int i = t + 256 * m;
    row[i] = re[i] * scale;
  }
}

// ---------------------------------------------------------------------------
extern "C" void kernel_launch(void* const* d_in, const int* in_sizes, int n_in,
                              void* d_out, int out_size, void* d_ws, size_t ws_size,
                              hipStream_t stream) {
  (void)in_sizes; (void)n_in; (void)out_size; (void)ws_size;
  const float* x  = (const float*)d_in[0];
  const float* Wq = (const float*)d_in[1];
  const float* Wk = (const float*)d_in[2];
  const float* Wv = (const float*)d_in[3];
  float* out = (float*)d_out;

  // Workspace budget (guard against OOB — R0's 169 MB overran ws and
  // corrupted neighboring allocations):
  //   KV/P half buffer: 4096 rows * 2048 floats = 33.55 MB
  //   csum:             64 * 1024 float2        =  0.52 MB
  // total ~34.1 MB.
  float*  KV   = (float*)d_ws;
  float2* csum = (float2*)((char*)d_ws + (size_t)MH * 2048 * sizeof(float));

  dim3 gb(16, 16);

  // q projection for ALL rows, directly into d_out (consumed in-place by unbind)
  gemm_nt<<<dim3(MM / 64, DD / 64, 1), gb, 0, stream>>>(x, Wq, Wq, out, DD);

  for (int h = 0; h < 2; ++h) {
    const float* xh   = x   + (size_t)h * MH * DD;
    float*       outh = out + (size_t)h * MH * DD;

    // k,v projections for this half, interleaved KV[row][2][1024]
    gemm_nt<<<dim3(MH / 64, DD / 64, 2), gb, 0, stream>>>(xh, Wk, Wv, KV, 2048);
    // P = FFT(k) * FFT(v), in place over KV
    bind_kernel<<<MH, 256, 0, stream>>>(KV);
    // causal cumsum over s, per (b, bin)
    scan_chunk_sum<<<64, 1024, 0, stream>>>((const float2*)KV, csum);
    scan_chunk_scan<<<2, 1024, 0, stream>>>(csum);
    scan_apply<<<64, 1024, 0, stream>>>((float2*)KV, csum);
    // out = Re(IFFT(mem * conj(FFT(q)))), in place on d_out rows
    unbind_kernel<<<MH, 256, 0, stream>>>(outh, (const float2*)KV);
  }
}

// Round 3
// 584.603 us; speedup vs baseline: 1.8082x; 1.8082x over previous
//
#include <hip/hip_runtime.h>

// Problem constants: B=4, S=2048, D=1024
#define BB 4
#define SS 2048
#define DD 1024
#define MQ 2048               // rows per quarter (= one batch); 4-pass pipeline keeps ws ~27.5 MB (< proven-safe 34 MB)
#define PI_F 3.14159265358979323846f

typedef __attribute__((ext_vector_type(8))) short bf16x8;
typedef __attribute__((ext_vector_type(4))) float f32x4;

// ---------------------------------------------------------------------------
// fp32 -> bf16 (round-to-nearest-even)
// ---------------------------------------------------------------------------
__device__ __forceinline__ unsigned short f2bf(float f) {
  unsigned int u = __float_as_uint(f);
  u = (u + 0x7FFFu + ((u >> 16) & 1u)) >> 16;
  return (unsigned short)u;
}

__global__ __launch_bounds__(256) void convert_bf16(
    const float* __restrict__ src, unsigned short* __restrict__ dst) {
  const long i = ((long)blockIdx.x * 256 + threadIdx.x) * 4;
  const float4 v = *(const float4*)&src[i];
  ushort4 o;
  o.x = f2bf(v.x); o.y = f2bf(v.y); o.z = f2bf(v.z); o.w = f2bf(v.w);
  *(ushort4*)&dst[i] = o;
}

// ---------------------------------------------------------------------------
// MFMA GEMM (m97 structure): C[m][n] = sum_k A[m][k] * W[n][k], A,W row-major
// bf16 inputs, fp32 out. 128x128 tile, BK=32, 256 thr = 4 waves (2x2), each
// wave 64x64 = 4x4 mfma_f32_16x16x32_bf16 tiles. 16B global_load_lds staging.
// grid.z: 0 -> q (into out rows, ldc=DD); 1 -> KV col 0 (k); 2 -> KV col 1024 (v).
// ---------------------------------------------------------------------------
__device__ __forceinline__ void async16(const void* g, void* l) {
  __builtin_amdgcn_global_load_lds(
      (const __attribute__((address_space(1))) void*)g,
      (__attribute__((address_space(3))) void*)l, 16, 0, 0);
}

__global__ __launch_bounds__(256) void gemm_mfma(
    const unsigned short* __restrict__ xb,   // [MQ][DD] bf16
    const unsigned short* __restrict__ Wb,   // [3][DD][DD] bf16 (q,k,v)
    float* __restrict__ outq,                // quarter's q rows (in d_out)
    float* __restrict__ KV) {                // [MQ][2*DD] fp32 interleaved k|v
  const int z = blockIdx.z;
  const unsigned short* W = Wb + (size_t)z * DD * DD;
  float* C = (z == 0) ? outq : (KV + (size_t)(z - 1) * DD);
  const long ldc = (z == 0) ? DD : 2 * DD;

  __shared__ unsigned short Als[128 * 32];  // 8 KB, row-major [row][32]
  __shared__ unsigned short Bls[128 * 32];  // 8 KB

  const int tid  = threadIdx.x;
  const int lane = tid & 63;
  const int wave = tid >> 6;
  const int wm = (wave & 1) * 64;
  const int wn = (wave >> 1) * 64;

  const long m0 = (long)blockIdx.x * 128;
  const long n0 = (long)blockIdx.y * 128;

  f32x4 acc[4][4] = {};   // [mt][nt]

  for (int k0 = 0; k0 < DD; k0 += 32) {
    // stage: 512 slots x 16B per tile; slot -> (row=slot>>2, kq=slot&3)
    #pragma unroll
    for (int i = 0; i < 2; ++i) {
      const int slot = i * 256 + tid;
      const int row  = slot >> 2;
      const int kq   = slot & 3;
      async16(xb + (m0 + row) * DD + k0 + kq * 8, &Als[slot * 8]);
      async16(W  + (n0 + row) * DD + k0 + kq * 8, &Bls[slot * 8]);
    }
    __syncthreads();   // drains vmcnt -> tiles ready

    const int fr = lane & 15;   // row within 16x16 frag
    const int kq = lane >> 4;   // k-quad: k = kq*8 .. kq*8+7
    bf16x8 af[4], bfr[4];
    #pragma unroll
    for (int mt = 0; mt < 4; ++mt)
      af[mt] = *(const bf16x8*)&Als[(wm + mt * 16 + fr) * 32 + kq * 8];
    #pragma unroll
    for (int nt = 0; nt < 4; ++nt)
      bfr[nt] = *(const bf16x8*)&Bls[(wn + nt * 16 + fr) * 32 + kq * 8];
    #pragma unroll
    for (int mt = 0; mt < 4; ++mt)
      #pragma unroll
      for (int nt = 0; nt < 4; ++nt)
        acc[mt][nt] = __builtin_amdgcn_mfma_f32_16x16x32_bf16(
            af[mt], bfr[nt], acc[mt][nt], 0, 0, 0);
    __syncthreads();   // all frag reads done before next overwrite
  }

  // epilogue: C/D layout col=lane&15, row=(lane>>4)*4+reg  [m89/m91 verified]
  const int col = lane & 15;
  const int r0  = (lane >> 4) * 4;
  #pragma unroll
  for (int mt = 0; mt < 4; ++mt)
    #pragma unroll
    for (int nt = 0; nt < 4; ++nt)
      #pragma unroll
      for (int r = 0; r < 4; ++r) {
        const long m = m0 + wm + mt * 16 + r0 + r;
        const long n = n0 + wn + nt * 16 + col;
        C[m * ldc + n] = acc[mt][nt][r];
      }
}

// ---------------------------------------------------------------------------
// FFT: N=1024, 256 thr, LDS re/im. Fwd = DIF (natural->bitrev), Inv = DIT
// (bitrev->natural). Middle of pipeline stays in bit-reversed bin order.
// ---------------------------------------------------------------------------
__device__ __forceinline__ void fft_dif_fwd(float* re, float* im,
                                            const float* twc, const float* tws,
                                            int t) {
  #pragma unroll
  for (int s = 10; s >= 1; --s) {
    const int half = 1 << (s - 1);
    #pragma unroll
    for (int r = 0; r < 2; ++r) {
      const int j   = t + (r << 8);
      const int pos = j & (half - 1);
      const int grp = j >> (s - 1);
      const int i1  = (grp << s) + pos;
      const int i2  = i1 + half;
      const int wi  = pos << (10 - s);
      const float c  = twc[wi];
      const float sn = tws[wi];
      const float ur = re[i1], ui = im[i1];
      const float xr = re[i2], xi = im[i2];
      const float dr = ur - xr, di = ui - xi;
      re[i1] = ur + xr;
      im[i1] = ui + xi;
      re[i2] = dr * c - di * sn;
      im[i2] = dr * sn + di * c;
    }
    __syncthreads();
  }
}

__device__ __forceinline__ void fft_dit_inv(float* re, float* im,
                                            const float* twc, const float* tws,
                                            int t) {
  #pragma unroll
  for (int s = 1; s <= 10; ++s) {
    const int half = 1 << (s - 1);
    #pragma unroll
    for (int r = 0; r < 2; ++r) {
      const int j   = t + (r << 8);
      const int pos = j & (half - 1);
      const int grp = j >> (s - 1);
      const int i1  = (grp << s) + pos;
      const int i2  = i1 + half;
      const int wi  = pos << (10 - s);
      const float c  = twc[wi];
      const float sn = -tws[wi];
      const float xr = re[i2], xi = im[i2];
      const float tr = xr * c - xi * sn;
      const float ti = xr * sn + xi * c;
      const float ur = re[i1], ui = im[i1];
      re[i1] = ur + tr;
      im[i1] = ui + ti;
      re[i2] = ur - tr;
      im[i2] = ui - ti;
    }
    __syncthreads();
  }
}

__device__ __forceinline__ void fill_twiddles(float* twc, float* tws, int t) {
  #pragma unroll
  for (int i = t; i < 512; i += 256) {
    float a = -2.0f * PI_F * (float)i / 1024.0f;
    float s, c;
    sincosf(a, &s, &c);
    twc[i] = c;
    tws[i] = s;
  }
}

// ---------------------------------------------------------------------------
// Bind (in place): KV row = [k(1024) | v(1024)] fp32 -> P = FFT(k)*FFT(v)
// as float2[1024] over the same 8 KB (bit-reversed bins).
// ---------------------------------------------------------------------------
__global__ __launch_bounds__(256) void bind_kernel(float* __restrict__ KV) {
  __shared__ float re[1024], im[1024];
  __shared__ float twc[512], tws[512];
  const int t = threadIdx.x;
  float* row = KV + (long)blockIdx.x * 2048;

  fill_twiddles(twc, tws, t);
  #pragma unroll
  for (int m = 0; m < 4; ++m) {
    const int i = t + 256 * m;
    re[i] = row[i];
    im[i] = 0.0f;
  }
  __syncthreads();
  fft_dif_fwd(re, im, twc, tws, t);

  float fkr[4], fki[4];
  #pragma unroll
  for (int m = 0; m < 4; ++m) {
    const int i = t + 256 * m;
    fkr[m] = re[i];
    fki[m] = im[i];
  }
  __syncthreads();
  #pragma unroll
  for (int m = 0; m < 4; ++m) {
    const int i = t + 256 * m;
    re[i] = row[1024 + i];
    im[i] = 0.0f;
  }
  __syncthreads();
  fft_dif_fwd(re, im, twc, tws, t);

  float2* P = (float2*)row;
  #pragma unroll
  for (int m = 0; m < 4; ++m) {
    const int i = t + 256 * m;
    const float vr = re[i], vi = im[i];
    P[i] = make_float2(fkr[m] * vr - fki[m] * vi,
                       fkr[m] * vi + fki[m] * vr);
  }
}

// ---------------------------------------------------------------------------
// Causal cumsum over s per bin (one batch): 3-pass chunked scan, 32 chunks x 64.
// ---------------------------------------------------------------------------
__global__ __launch_bounds__(1024) void scan_chunk_sum(
    const float2* __restrict__ P, float2* __restrict__ csum) {
  const int chunk = blockIdx.x;       // 0..31
  const int f = threadIdx.x;          // 0..1023
  long base = (long)chunk * 64 * DD + f;
  float sr = 0.0f, si = 0.0f;
  for (int i = 0; i < 64; ++i) {
    float2 p = P[base + (long)i * DD];
    sr += p.x; si += p.y;
  }
  csum[(long)chunk * DD + f] = make_float2(sr, si);
}

__global__ __launch_bounds__(1024) void scan_chunk_scan(float2* csum) {
  const int f = threadIdx.x;
  float rr = 0.0f, ri = 0.0f;
  for (int c = 0; c < 32; ++c) {
    const long o = (long)c * DD + f;
    float2 v = csum[o];
    csum[o] = make_float2(rr, ri);    // exclusive scan of chunk sums
    rr += v.x; ri += v.y;
  }
}

__global__ __launch_bounds__(1024) void scan_apply(
    float2* __restrict__ P, const float2* __restrict__ csum) {
  const int chunk = blockIdx.x;
  const int f = threadIdx.x;
  float2 off = csum[(long)chunk * DD + f];
  float ar = off.x, ai = off.y;
  long base = (long)chunk * 64 * DD + f;
  for (int i = 0; i < 64; ++i) {
    const long o = base + (long)i * DD;
    float2 p = P[o];
    ar += p.x; ai += p.y;
    P[o] = make_float2(ar, ai);       // inclusive cumsum
  }
}

// ---------------------------------------------------------------------------
// Unbind (in place on d_out rows): fq = FFT(q); z = mem*conj(fq);
// row = Re(IFFT(z)).
// ---------------------------------------------------------------------------
__global__ __launch_bounds__(256) void unbind_kernel(
    float* __restrict__ qout, const float2* __restrict__ mem) {
  __shared__ float re[1024], im[1024];
  __shared__ float twc[512], tws[512];
  const int t = threadIdx.x;
  float* row = qout + (long)blockIdx.x * DD;
  const float2* mrow = mem + (long)blockIdx.x * DD;

  fill_twiddles(twc, tws, t);
  #pragma unroll
  for (int m = 0; m < 4; ++m) {
    const int i = t + 256 * m;
    re[i] = row[i];
    im[i] = 0.0f;
  }
  __syncthreads();
  fft_dif_fwd(re, im, twc, tws, t);

  float zr[4], zi[4];
  #pragma unroll
  for (int m = 0; m < 4; ++m) {
    const int i = t + 256 * m;
    const float fr = re[i], fi = im[i];
    const float2 mv = mrow[i];
    zr[m] = mv.x * fr + mv.y * fi;
    zi[m] = mv.y * fr - mv.x * fi;
  }
  __syncthreads();
  #pragma unroll
  for (int m = 0; m < 4; ++m) {
    const int i = t + 256 * m;
    re[i] = zr[m];
    im[i] = zi[m];
  }
  __syncthreads();
  fft_dit_inv(re, im, twc, tws, t);

  const float scale = 1.0f / 1024.0f;
  #pragma unroll
  for (int m = 0; m < 4; ++m) {
    const int i = t + 256 * m;
    row[i] = re[i] * scale;
  }
}

// ---------------------------------------------------------------------------
extern "C" void kernel_launch(void* const* d_in, const int* in_sizes, int n_in,
                              void* d_out, int out_size, void* d_ws, size_t ws_size,
                              hipStream_t stream) {
  (void)in_sizes; (void)n_in; (void)out_size; (void)ws_size;
  const float* x  = (const float*)d_in[0];
  const float* Wq = (const float*)d_in[1];
  const float* Wk = (const float*)d_in[2];
  const float* Wv = (const float*)d_in[3];
  float* out = (float*)d_out;

  // ws layout (27.5 MB total, proven-safe budget is ~34 MB):
  //   Wb  : 3*1024*1024 bf16 = 6.29 MB
  //   xb  : 2048*1024  bf16  = 4.19 MB
  //   KV/P: 2048*2048  fp32  = 16.78 MB
  //   csum: 32*1024 float2   = 0.26 MB
  char* ws = (char*)d_ws;
  unsigned short* Wb = (unsigned short*)ws;
  unsigned short* xb = (unsigned short*)(ws + (size_t)3 * DD * DD * 2);
  float*          KV = (float*)(ws + (size_t)3 * DD * DD * 2 + (size_t)MQ * DD * 2);
  float2*       csum = (float2*)((char*)KV + (size_t)MQ * 2 * DD * 4);

  // weights -> bf16 (q,k,v packed)
  convert_bf16<<<DD * DD / 1024, 256, 0, stream>>>(Wq, Wb);
  convert_bf16<<<DD * DD / 1024, 256, 0, stream>>>(Wk, Wb + (size_t)DD * DD);
  convert_bf16<<<DD * DD / 1024, 256, 0, stream>>>(Wv, Wb + (size_t)2 * DD * DD);

  for (int b = 0; b < 4; ++b) {
    const float* xq   = x   + (size_t)b * MQ * DD;
    float*       outq = out + (size_t)b * MQ * DD;

    convert_bf16<<<MQ * DD / 1024, 256, 0, stream>>>(xq, xb);
    // q,k,v projections: z=0 -> q into out rows; z=1,2 -> KV interleaved
    gemm_mfma<<<dim3(MQ / 128, DD / 128, 3), 256, 0, stream>>>(xb, Wb, outq, KV);
    // P = FFT(k)*FFT(v) in place
    bind_kernel<<<MQ, 256, 0, stream>>>(KV);
    // causal cumsum over s
    scan_chunk_sum<<<32, 1024, 0, stream>>>((const float2*)KV, csum);
    scan_chunk_scan<<<1, 1024, 0, stream>>>(csum);
    scan_apply<<<32, 1024, 0, stream>>>((float2*)KV, csum);
    // out = Re(IFFT(mem * conj(FFT(q)))) in place
    unbind_kernel<<<MQ, 256, 0, stream>>>(outq, (const float2*)KV);
  }
}

// Round 4
// 466.801 us; speedup vs baseline: 2.2645x; 1.2524x over previous
//
#include <hip/hip_runtime.h>

// Problem constants: B=4, S=2048, D=1024
#define BB 4
#define SS 2048
#define DD 1024
#define MQ 2048               // rows per quarter (= one batch)
#define CH 64                 // scan chunks per quarter
#define RR 32                 // rows per chunk (CH*RR = MQ)
#define PI_F 3.14159265358979323846f

typedef __attribute__((ext_vector_type(8))) short bf16x8;
typedef __attribute__((ext_vector_type(4))) float f32x4;

// ---------------------------------------------------------------------------
// fp32 -> bf16 (round-to-nearest-even)
// ---------------------------------------------------------------------------
__device__ __forceinline__ unsigned short f2bf(float f) {
  unsigned int u = __float_as_uint(f);
  u = (u + 0x7FFFu + ((u >> 16) & 1u)) >> 16;
  return (unsigned short)u;
}

__global__ __launch_bounds__(256) void convert_bf16(
    const float* __restrict__ src, unsigned short* __restrict__ dst) {
  const long i = ((long)blockIdx.x * 256 + threadIdx.x) * 4;
  const float4 v = *(const float4*)&src[i];
  ushort4 o;
  o.x = f2bf(v.x); o.y = f2bf(v.y); o.z = f2bf(v.z); o.w = f2bf(v.w);
  *(ushort4*)&dst[i] = o;
}

// all three weight matrices in one launch (grid.y = 0,1,2)
__global__ __launch_bounds__(256) void convert_w(
    const float* __restrict__ Wq, const float* __restrict__ Wk,
    const float* __restrict__ Wv, unsigned short* __restrict__ dst) {
  const int z = blockIdx.y;
  const float* src = (z == 0) ? Wq : (z == 1) ? Wk : Wv;
  const long i = ((long)blockIdx.x * 256 + threadIdx.x) * 4;
  const float4 v = *(const float4*)&src[i];
  ushort4 o;
  o.x = f2bf(v.x); o.y = f2bf(v.y); o.z = f2bf(v.z); o.w = f2bf(v.w);
  *(ushort4*)&dst[(size_t)z * DD * DD + i] = o;
}

// ---------------------------------------------------------------------------
// MFMA GEMM (m97 structure): C[m][n] = sum_k A[m][k] * W[n][k], bf16 in,
// fp32 out. 128x128 tile, BK=32, 256 thr = 4 waves, 16B global_load_lds.
// grid.z: 0 -> q (ldc=DD, into d_out rows); 1,2 -> KV interleaved (ldc=2DD).
// ---------------------------------------------------------------------------
__device__ __forceinline__ void async16(const void* g, void* l) {
  __builtin_amdgcn_global_load_lds(
      (const __attribute__((address_space(1))) void*)g,
      (__attribute__((address_space(3))) void*)l, 16, 0, 0);
}

__global__ __launch_bounds__(256) void gemm_mfma(
    const unsigned short* __restrict__ xb,
    const unsigned short* __restrict__ Wb,
    float* __restrict__ outq, float* __restrict__ KV) {
  const int z = blockIdx.z;
  const unsigned short* W = Wb + (size_t)z * DD * DD;
  float* C = (z == 0) ? outq : (KV + (size_t)(z - 1) * DD);
  const long ldc = (z == 0) ? DD : 2 * DD;

  __shared__ unsigned short Als[128 * 32];
  __shared__ unsigned short Bls[128 * 32];

  const int tid  = threadIdx.x;
  const int lane = tid & 63;
  const int wave = tid >> 6;
  const int wm = (wave & 1) * 64;
  const int wn = (wave >> 1) * 64;

  const long m0 = (long)blockIdx.x * 128;
  const long n0 = (long)blockIdx.y * 128;

  f32x4 acc[4][4] = {};

  for (int k0 = 0; k0 < DD; k0 += 32) {
    #pragma unroll
    for (int i = 0; i < 2; ++i) {
      const int slot = i * 256 + tid;
      const int row  = slot >> 2;
      const int kq   = slot & 3;
      async16(xb + (m0 + row) * DD + k0 + kq * 8, &Als[slot * 8]);
      async16(W  + (n0 + row) * DD + k0 + kq * 8, &Bls[slot * 8]);
    }
    __syncthreads();

    const int fr = lane & 15;
    const int kq = lane >> 4;
    bf16x8 af[4], bfr[4];
    #pragma unroll
    for (int mt = 0; mt < 4; ++mt)
      af[mt] = *(const bf16x8*)&Als[(wm + mt * 16 + fr) * 32 + kq * 8];
    #pragma unroll
    for (int nt = 0; nt < 4; ++nt)
      bfr[nt] = *(const bf16x8*)&Bls[(wn + nt * 16 + fr) * 32 + kq * 8];
    #pragma unroll
    for (int mt = 0; mt < 4; ++mt)
      #pragma unroll
      for (int nt = 0; nt < 4; ++nt)
        acc[mt][nt] = __builtin_amdgcn_mfma_f32_16x16x32_bf16(
            af[mt], bfr[nt], acc[mt][nt], 0, 0, 0);
    __syncthreads();
  }

  const int col = lane & 15;
  const int r0  = (lane >> 4) * 4;
  #pragma unroll
  for (int mt = 0; mt < 4; ++mt)
    #pragma unroll
    for (int nt = 0; nt < 4; ++nt)
      #pragma unroll
      for (int r = 0; r < 4; ++r) {
        const long m = m0 + wm + mt * 16 + r0 + r;
        const long n = n0 + wn + nt * 16 + col;
        C[m * ldc + n] = acc[mt][nt][r];
      }
}

// ---------------------------------------------------------------------------
// FFT: N=1024, 256 thr, LDS. Fwd = DIF (natural->bitrev), Inv = DIT
// (bitrev->natural). Pipeline middle stays in bit-reversed bin order.
// ---------------------------------------------------------------------------
__device__ __forceinline__ void fft_dif_fwd(float* re, float* im,
                                            const float* twc, const float* tws,
                                            int t) {
  #pragma unroll
  for (int s = 10; s >= 1; --s) {
    const int half = 1 << (s - 1);
    #pragma unroll
    for (int r = 0; r < 2; ++r) {
      const int j   = t + (r << 8);
      const int pos = j & (half - 1);
      const int grp = j >> (s - 1);
      const int i1  = (grp << s) + pos;
      const int i2  = i1 + half;
      const int wi  = pos << (10 - s);
      const float c  = twc[wi];
      const float sn = tws[wi];
      const float ur = re[i1], ui = im[i1];
      const float xr = re[i2], xi = im[i2];
      const float dr = ur - xr, di = ui - xi;
      re[i1] = ur + xr;
      im[i1] = ui + xi;
      re[i2] = dr * c - di * sn;
      im[i2] = dr * sn + di * c;
    }
    __syncthreads();
  }
}

__device__ __forceinline__ void fft_dit_inv(float* re, float* im,
                                            const float* twc, const float* tws,
                                            int t) {
  #pragma unroll
  for (int s = 1; s <= 10; ++s) {
    const int half = 1 << (s - 1);
    #pragma unroll
    for (int r = 0; r < 2; ++r) {
      const int j   = t + (r << 8);
      const int pos = j & (half - 1);
      const int grp = j >> (s - 1);
      const int i1  = (grp << s) + pos;
      const int i2  = i1 + half;
      const int wi  = pos << (10 - s);
      const float c  = twc[wi];
      const float sn = -tws[wi];
      const float xr = re[i2], xi = im[i2];
      const float tr = xr * c - xi * sn;
      const float ti = xr * sn + xi * c;
      const float ur = re[i1], ui = im[i1];
      re[i1] = ur + tr;
      im[i1] = ui + ti;
      re[i2] = ur - tr;
      im[i2] = ui - ti;
    }
    __syncthreads();
  }
}

__device__ __forceinline__ void fill_twiddles(float* twc, float* tws, int t) {
  #pragma unroll
  for (int i = t; i < 512; i += 256) {
    float a = -2.0f * PI_F * (float)i / 1024.0f;
    float s, c;
    sincosf(a, &s, &c);
    twc[i] = c;
    tws[i] = s;
  }
}

// ---------------------------------------------------------------------------
// Bind (in place): k,v real -> ONE complex FFT of w = k + i*v, then
// Hermitian split recovers fk,fv; P = fk*fv over the same 8 KB row.
// Bit-reversed order: partner of LDS index j is j2 = brev(( N - brev(j) )&(N-1)).
// ---------------------------------------------------------------------------
__global__ __launch_bounds__(256) void bind_kernel(float* __restrict__ KV) {
  __shared__ float re[1024], im[1024];
  __shared__ float twc[512], tws[512];
  const int t = threadIdx.x;
  float* row = KV + (long)blockIdx.x * 2048;

  fill_twiddles(twc, tws, t);
  #pragma unroll
  for (int m = 0; m < 4; ++m) {
    const int i = t + 256 * m;
    re[i] = row[i];           // k
    im[i] = row[1024 + i];    // v
  }
  __syncthreads();
  fft_dif_fwd(re, im, twc, tws, t);   // ends with __syncthreads

  float2 Pv[4];
  #pragma unroll
  for (int m = 0; m < 4; ++m) {
    const int j  = t + 256 * m;
    const unsigned n  = __brev((unsigned)j) >> 22;         // bin of index j
    const int j2 = (int)(__brev((1024u - n) & 1023u) >> 22);
    const float Fr1 = re[j],  Fi1 = im[j];
    const float Fr2 = re[j2], Fi2 = im[j2];
    const float fkr = 0.5f * (Fr1 + Fr2);
    const float fki = 0.5f * (Fi1 - Fi2);
    const float fvr = 0.5f * (Fi1 + Fi2);
    const float fvi = 0.5f * (Fr2 - Fr1);
    Pv[m] = make_float2(fkr * fvr - fki * fvi, fkr * fvi + fki * fvr);
  }
  float2* P = (float2*)row;   // all row reads done before FFT
  #pragma unroll
  for (int m = 0; m < 4; ++m) P[t + 256 * m] = Pv[m];
}

// ---------------------------------------------------------------------------
// Causal cumsum over s per bin: 3-pass chunked scan, CH=64 chunks x RR=32 rows.
// Grids sized for full 256-CU coverage (R3's 32-block grids ran at 1/8 BW).
// ---------------------------------------------------------------------------
__global__ __launch_bounds__(256) void scan_chunk_sum(
    const float2* __restrict__ P, float2* __restrict__ csum) {
  const int chunk = blockIdx.x;                      // 0..63
  const int f = blockIdx.y * 256 + threadIdx.x;      // bin 0..1023
  long base = (long)chunk * RR * DD + f;
  float sr = 0.0f, si = 0.0f;
  #pragma unroll 4
  for (int i = 0; i < RR; ++i) {
    float2 p = P[base + (long)i * DD];
    sr += p.x; si += p.y;
  }
  csum[(long)chunk * DD + f] = make_float2(sr, si);
}

__global__ __launch_bounds__(256) void scan_chunk_scan(float2* csum) {
  const int f = blockIdx.x * 256 + threadIdx.x;
  float2 v[CH];
  #pragma unroll
  for (int c = 0; c < CH; ++c) v[c] = csum[(long)c * DD + f];  // all in flight
  float rr = 0.0f, ri = 0.0f;
  #pragma unroll
  for (int c = 0; c < CH; ++c) {
    const float2 x = v[c];
    csum[(long)c * DD + f] = make_float2(rr, ri);              // exclusive
    rr += x.x; ri += x.y;
  }
}

__global__ __launch_bounds__(256) void scan_apply(
    float2* __restrict__ P, const float2* __restrict__ csum) {
  const int chunk = blockIdx.x;
  const int f = blockIdx.y * 256 + threadIdx.x;
  float2 off = csum[(long)chunk * DD + f];
  float ar = off.x, ai = off.y;
  long base = (long)chunk * RR * DD + f;
  for (int i = 0; i < RR; ++i) {
    const long o = base + (long)i * DD;
    float2 p = P[o];
    ar += p.x; ai += p.y;
    P[o] = make_float2(ar, ai);       // inclusive cumsum
  }
}

// ---------------------------------------------------------------------------
// Unbind (in place on d_out rows): fq = FFT(q); z = mem*conj(fq);
// row = Re(IFFT(z)).
// ---------------------------------------------------------------------------
__global__ __launch_bounds__(256) void unbind_kernel(
    float* __restrict__ qout, const float2* __restrict__ mem) {
  __shared__ float re[1024], im[1024];
  __shared__ float twc[512], tws[512];
  const int t = threadIdx.x;
  float* row = qout + (long)blockIdx.x * DD;
  const float2* mrow = mem + (long)blockIdx.x * DD;

  fill_twiddles(twc, tws, t);
  #pragma unroll
  for (int m = 0; m < 4; ++m) {
    const int i = t + 256 * m;
    re[i] = row[i];
    im[i] = 0.0f;
  }
  __syncthreads();
  fft_dif_fwd(re, im, twc, tws, t);

  float zr[4], zi[4];
  #pragma unroll
  for (int m = 0; m < 4; ++m) {
    const int i = t + 256 * m;
    const float fr = re[i], fi = im[i];
    const float2 mv = mrow[i];
    zr[m] = mv.x * fr + mv.y * fi;
    zi[m] = mv.y * fr - mv.x * fi;
  }
  __syncthreads();
  #pragma unroll
  for (int m = 0; m < 4; ++m) {
    const int i = t + 256 * m;
    re[i] = zr[m];
    im[i] = zi[m];
  }
  __syncthreads();
  fft_dit_inv(re, im, twc, tws, t);

  const float scale = 1.0f / 1024.0f;
  #pragma unroll
  for (int m = 0; m < 4; ++m) {
    const int i = t + 256 * m;
    row[i] = re[i] * scale;
  }
}

// ---------------------------------------------------------------------------
extern "C" void kernel_launch(void* const* d_in, const int* in_sizes, int n_in,
                              void* d_out, int out_size, void* d_ws, size_t ws_size,
                              hipStream_t stream) {
  (void)in_sizes; (void)n_in; (void)out_size; (void)ws_size;
  const float* x  = (const float*)d_in[0];
  const float* Wq = (const float*)d_in[1];
  const float* Wk = (const float*)d_in[2];
  const float* Wv = (const float*)d_in[3];
  float* out = (float*)d_out;

  // ws layout (~27.8 MB; proven-safe budget ~34 MB):
  //   Wb  : 3*1024*1024 bf16 = 6.29 MB
  //   xb  : 2048*1024  bf16  = 4.19 MB
  //   KV/P: 2048*2048  fp32  = 16.78 MB
  //   csum: 64*1024 float2   = 0.52 MB
  char* ws = (char*)d_ws;
  unsigned short* Wb = (unsigned short*)ws;
  unsigned short* xb = (unsigned short*)(ws + (size_t)3 * DD * DD * 2);
  float*          KV = (float*)(ws + (size_t)3 * DD * DD * 2 + (size_t)MQ * DD * 2);
  float2*       csum = (float2*)((char*)KV + (size_t)MQ * 2 * DD * 4);

  convert_w<<<dim3(DD * DD / 1024, 3), 256, 0, stream>>>(Wq, Wk, Wv, Wb);

  for (int b = 0; b < 4; ++b) {
    const float* xq   = x   + (size_t)b * MQ * DD;
    float*       outq = out + (size_t)b * MQ * DD;

    convert_bf16<<<MQ * DD / 1024, 256, 0, stream>>>(xq, xb);
    gemm_mfma<<<dim3(MQ / 128, DD / 128, 3), 256, 0, stream>>>(xb, Wb, outq, KV);
    bind_kernel<<<MQ, 256, 0, stream>>>(KV);
    scan_chunk_sum<<<dim3(CH, 4), 256, 0, stream>>>((const float2*)KV, csum);
    scan_chunk_scan<<<4, 256, 0, stream>>>(csum);
    scan_apply<<<dim3(CH, 4), 256, 0, stream>>>((float2*)KV, csum);
    unbind_kernel<<<MQ, 256, 0, stream>>>(outq, (const float2*)KV);
  }
}

// Round 5
// 378.039 us; speedup vs baseline: 2.7962x; 1.2348x over previous
//
#include <hip/hip_runtime.h>

// Problem constants: B=4, S=2048, D=1024
#define BB 4
#define SS 2048
#define DD 1024
#define MQ 2048               // rows per quarter (= one batch)
#define CH 64                 // scan chunks per quarter
#define RR 32                 // rows per chunk (CH*RR = MQ)
#define PI_F 3.14159265358979323846f

typedef __attribute__((ext_vector_type(8))) short bf16x8;
typedef __attribute__((ext_vector_type(4))) float f32x4;

// ---------------------------------------------------------------------------
// fp32 -> bf16 (round-to-nearest-even)
// ---------------------------------------------------------------------------
__device__ __forceinline__ unsigned short f2bf(float f) {
  unsigned int u = __float_as_uint(f);
  u = (u + 0x7FFFu + ((u >> 16) & 1u)) >> 16;
  return (unsigned short)u;
}

__global__ __launch_bounds__(256) void convert_bf16(
    const float* __restrict__ src, unsigned short* __restrict__ dst) {
  const long i = ((long)blockIdx.x * 256 + threadIdx.x) * 4;
  const float4 v = *(const float4*)&src[i];
  ushort4 o;
  o.x = f2bf(v.x); o.y = f2bf(v.y); o.z = f2bf(v.z); o.w = f2bf(v.w);
  *(ushort4*)&dst[i] = o;
}

__global__ __launch_bounds__(256) void convert_w(
    const float* __restrict__ Wq, const float* __restrict__ Wk,
    const float* __restrict__ Wv, unsigned short* __restrict__ dst) {
  const int z = blockIdx.y;
  const float* src = (z == 0) ? Wq : (z == 1) ? Wk : Wv;
  const long i = ((long)blockIdx.x * 256 + threadIdx.x) * 4;
  const float4 v = *(const float4*)&src[i];
  ushort4 o;
  o.x = f2bf(v.x); o.y = f2bf(v.y); o.z = f2bf(v.z); o.w = f2bf(v.w);
  *(ushort4*)&dst[(size_t)z * DD * DD + i] = o;
}

// ---------------------------------------------------------------------------
// MFMA GEMM (m97 structure), unchanged from R4 (known-good).
// ---------------------------------------------------------------------------
__device__ __forceinline__ void async16(const void* g, void* l) {
  __builtin_amdgcn_global_load_lds(
      (const __attribute__((address_space(1))) void*)g,
      (__attribute__((address_space(3))) void*)l, 16, 0, 0);
}

__global__ __launch_bounds__(256) void gemm_mfma(
    const unsigned short* __restrict__ xb,
    const unsigned short* __restrict__ Wb,
    float* __restrict__ outq, float* __restrict__ KV) {
  const int z = blockIdx.z;
  const unsigned short* W = Wb + (size_t)z * DD * DD;
  float* C = (z == 0) ? outq : (KV + (size_t)(z - 1) * DD);
  const long ldc = (z == 0) ? DD : 2 * DD;

  __shared__ unsigned short Als[128 * 32];
  __shared__ unsigned short Bls[128 * 32];

  const int tid  = threadIdx.x;
  const int lane = tid & 63;
  const int wave = tid >> 6;
  const int wm = (wave & 1) * 64;
  const int wn = (wave >> 1) * 64;

  const long m0 = (long)blockIdx.x * 128;
  const long n0 = (long)blockIdx.y * 128;

  f32x4 acc[4][4] = {};

  for (int k0 = 0; k0 < DD; k0 += 32) {
    #pragma unroll
    for (int i = 0; i < 2; ++i) {
      const int slot = i * 256 + tid;
      const int row  = slot >> 2;
      const int kq   = slot & 3;
      async16(xb + (m0 + row) * DD + k0 + kq * 8, &Als[slot * 8]);
      async16(W  + (n0 + row) * DD + k0 + kq * 8, &Bls[slot * 8]);
    }
    __syncthreads();

    const int fr = lane & 15;
    const int kq = lane >> 4;
    bf16x8 af[4], bfr[4];
    #pragma unroll
    for (int mt = 0; mt < 4; ++mt)
      af[mt] = *(const bf16x8*)&Als[(wm + mt * 16 + fr) * 32 + kq * 8];
    #pragma unroll
    for (int nt = 0; nt < 4; ++nt)
      bfr[nt] = *(const bf16x8*)&Bls[(wn + nt * 16 + fr) * 32 + kq * 8];
    #pragma unroll
    for (int mt = 0; mt < 4; ++mt)
      #pragma unroll
      for (int nt = 0; nt < 4; ++nt)
        acc[mt][nt] = __builtin_amdgcn_mfma_f32_16x16x32_bf16(
            af[mt], bfr[nt], acc[mt][nt], 0, 0, 0);
    __syncthreads();
  }

  const int col = lane & 15;
  const int r0  = (lane >> 4) * 4;
  #pragma unroll
  for (int mt = 0; mt < 4; ++mt)
    #pragma unroll
    for (int nt = 0; nt < 4; ++nt)
      #pragma unroll
      for (int r = 0; r < 4; ++r) {
        const long m = m0 + wm + mt * 16 + r0 + r;
        const long n = n0 + wn + nt * 16 + col;
        C[m * ldc + n] = acc[mt][nt][r];
      }
}

// ---------------------------------------------------------------------------
// Radix-4 FFT, N=1024, 256 threads, 4 complex/thread in registers.
// Forward DIF: stage strides 256,64,16,4,1; output in base-4 digit-reversed
// order. Inverse DIT: strides 1..256, consumes that order, natural output.
// Per-stage element positions: blk*4S + (t&(S-1)) + n*S, blk = t/S.
// Twiddles: one __sincosf per stage + complex squares (no LDS table).
// LDS buffer padded 1 float2 per 64 to break power-of-2 bank strides.
// ---------------------------------------------------------------------------
__device__ __forceinline__ int pidx(int i) { return i + (i >> 6); }
#define BUFSZ 1040   // 1024 + 16 pads

__device__ __forceinline__ int rev4(int p) {   // reverse 5 base-4 digits
  unsigned r = __brev((unsigned)p) >> 22;      // 10-bit bit reversal
  return (int)(((r & 0x155u) << 1) | ((r & 0x2AAu) >> 1));
}

__host__ __device__ constexpr int clog2(int s) {
  return (s == 256) ? 8 : (s == 64) ? 6 : (s == 16) ? 4 : (s == 4) ? 2 : 0;
}

template <int S>
__device__ __forceinline__ void fwd_stage(float2 x[4], int t) {
  float c1 = 1.0f, s1 = 0.0f;
  if (S > 1) {
    const int j = t & (S - 1);
    __sincosf(-2.0f * PI_F * (float)j / (float)(4 * S), &s1, &c1);
  }
  const float c2 = c1 * c1 - s1 * s1, s2 = 2.0f * c1 * s1;
  const float c3 = c1 * c2 - s1 * s2, s3 = c1 * s2 + s1 * c2;
  const float Ar = x[0].x + x[2].x, Ai = x[0].y + x[2].y;
  const float Br = x[1].x + x[3].x, Bi = x[1].y + x[3].y;
  const float Cr = x[0].x - x[2].x, Ci = x[0].y - x[2].y;
  const float dr = x[1].x - x[3].x, di = x[1].y - x[3].y;
  // D = -i*(x1-x3) = (di, -dr)
  const float y1r = Cr + di, y1i = Ci - dr;
  const float y2r = Ar - Br, y2i = Ai - Bi;
  const float y3r = Cr - di, y3i = Ci + dr;
  x[0] = make_float2(Ar + Br, Ai + Bi);
  x[1] = make_float2(y1r * c1 - y1i * s1, y1r * s1 + y1i * c1);
  x[2] = make_float2(y2r * c2 - y2i * s2, y2r * s2 + y2i * c2);
  x[3] = make_float2(y3r * c3 - y3i * s3, y3r * s3 + y3i * c3);
}

template <int S>
__device__ __forceinline__ void inv_stage(float2 x[4], int t) {
  float c1 = 1.0f, s1 = 0.0f;
  if (S > 1) {
    const int j = t & (S - 1);
    __sincosf(2.0f * PI_F * (float)j / (float)(4 * S), &s1, &c1);
  }
  const float c2 = c1 * c1 - s1 * s1, s2 = 2.0f * c1 * s1;
  const float c3 = c1 * c2 - s1 * s2, s3 = c1 * s2 + s1 * c2;
  const float u0r = x[0].x,                   u0i = x[0].y;
  const float u1r = x[1].x * c1 - x[1].y * s1, u1i = x[1].x * s1 + x[1].y * c1;
  const float u2r = x[2].x * c2 - x[2].y * s2, u2i = x[2].x * s2 + x[2].y * c2;
  const float u3r = x[3].x * c3 - x[3].y * s3, u3i = x[3].x * s3 + x[3].y * c3;
  const float Er = u0r + u2r, Ei = u0i + u2i;
  const float Fr = u0r - u2r, Fi = u0i - u2i;
  const float Gr = u1r + u3r, Gi = u1i + u3i;
  const float Hr = u1r - u3r, Hi = u1i - u3i;
  x[0] = make_float2(Er + Gr, Ei + Gi);
  x[1] = make_float2(Fr - Hi, Fi + Hr);   // F + iH
  x[2] = make_float2(Er - Gr, Ei - Gi);
  x[3] = make_float2(Fr + Hi, Fi - Hr);   // F - iH
}

// write regs at stage-SW positions, barrier, read at stage-SR positions, barrier
template <int SW, int SR>
__device__ __forceinline__ void xchg(float2* buf, float2 x[4], int t) {
  constexpr int LW = clog2(SW), LR = clog2(SR);
  #pragma unroll
  for (int n = 0; n < 4; ++n)
    buf[pidx(((t >> LW) << (LW + 2)) + (t & (SW - 1)) + n * SW)] = x[n];
  __syncthreads();
  #pragma unroll
  for (int n = 0; n < 4; ++n)
    x[n] = buf[pidx(((t >> LR) << (LR + 2)) + (t & (SR - 1)) + n * SR)];
  __syncthreads();
}

__device__ __forceinline__ void fwd_fft(float2* buf, float2 x[4], int t) {
  fwd_stage<256>(x, t); xchg<256, 64>(buf, x, t);
  fwd_stage<64>(x, t);  xchg<64, 16>(buf, x, t);
  fwd_stage<16>(x, t);  xchg<16, 4>(buf, x, t);
  fwd_stage<4>(x, t);   xchg<4, 1>(buf, x, t);
  fwd_stage<1>(x, t);
  #pragma unroll
  for (int n = 0; n < 4; ++n) buf[pidx(4 * t + n)] = x[n];  // scrambled order
  __syncthreads();
}

// ---------------------------------------------------------------------------
// Bind (in place): KV row = [k|v] fp32. One complex FFT of k+iv, Hermitian
// split (partner via rev4), P = fk*fv written over the same 8 KB row.
// ---------------------------------------------------------------------------
__global__ __launch_bounds__(256) void bind_kernel(float* __restrict__ KV) {
  __shared__ float2 buf[BUFSZ];
  const int t = threadIdx.x;
  float* row = KV + (long)blockIdx.x * 2048;

  float2 x[4];
  #pragma unroll
  for (int n = 0; n < 4; ++n) {
    const int i = t + 256 * n;
    x[n] = make_float2(row[i], row[1024 + i]);   // k + i*v
  }
  fwd_fft(buf, x, t);

  float2* P = (float2*)row;
  #pragma unroll
  for (int m = 0; m < 4; ++m) {
    const int p   = t + 256 * m;
    const int bin = rev4(p);
    const int p2  = rev4((1024 - bin) & 1023);
    const float2 F1 = buf[pidx(p)], F2 = buf[pidx(p2)];
    const float fkr = 0.5f * (F1.x + F2.x), fki = 0.5f * (F1.y - F2.y);
    const float fvr = 0.5f * (F1.y + F2.y), fvi = 0.5f * (F2.x - F1.x);
    P[p] = make_float2(fkr * fvr - fki * fvi, fkr * fvi + fki * fvr);
  }
}

// ---------------------------------------------------------------------------
// Scan kernels (unchanged, known-good).
// ---------------------------------------------------------------------------
__global__ __launch_bounds__(256) void scan_chunk_sum(
    const float2* __restrict__ P, float2* __restrict__ csum) {
  const int chunk = blockIdx.x;
  const int f = blockIdx.y * 256 + threadIdx.x;
  long base = (long)chunk * RR * DD + f;
  float sr = 0.0f, si = 0.0f;
  #pragma unroll 4
  for (int i = 0; i < RR; ++i) {
    float2 p = P[base + (long)i * DD];
    sr += p.x; si += p.y;
  }
  csum[(long)chunk * DD + f] = make_float2(sr, si);
}

__global__ __launch_bounds__(256) void scan_chunk_scan(float2* csum) {
  const int f = blockIdx.x * 256 + threadIdx.x;
  float2 v[CH];
  #pragma unroll
  for (int c = 0; c < CH; ++c) v[c] = csum[(long)c * DD + f];
  float rr = 0.0f, ri = 0.0f;
  #pragma unroll
  for (int c = 0; c < CH; ++c) {
    const float2 x = v[c];
    csum[(long)c * DD + f] = make_float2(rr, ri);
    rr += x.x; ri += x.y;
  }
}

__global__ __launch_bounds__(256) void scan_apply(
    float2* __restrict__ P, const float2* __restrict__ csum) {
  const int chunk = blockIdx.x;
  const int f = blockIdx.y * 256 + threadIdx.x;
  float2 off = csum[(long)chunk * DD + f];
  float ar = off.x, ai = off.y;
  long base = (long)chunk * RR * DD + f;
  for (int i = 0; i < RR; ++i) {
    const long o = base + (long)i * DD;
    float2 p = P[o];
    ar += p.x; ai += p.y;
    P[o] = make_float2(ar, ai);
  }
}

// ---------------------------------------------------------------------------
// Unbind, 2 rows/block (in place on d_out): q rows real -> one fwd FFT of
// q0+i*q1 (Hermitian split gives fq0,fq1); z0,z1 are conj-symmetric so one
// inverse FFT of z0+i*z1 gives out0 = Re, out1 = Im.
// ---------------------------------------------------------------------------
__global__ __launch_bounds__(256) void unbind_kernel(
    float* __restrict__ qout, const float2* __restrict__ mem) {
  __shared__ float2 buf[BUFSZ];
  const int t = threadIdx.x;
  const long r0 = (long)blockIdx.x * 2;
  float* row0 = qout + r0 * DD;
  float* row1 = row0 + DD;
  const float2* mem0 = mem + r0 * DD;
  const float2* mem1 = mem0 + DD;

  float2 x[4];
  #pragma unroll
  for (int n = 0; n < 4; ++n) {
    const int i = t + 256 * n;
    x[n] = make_float2(row0[i], row1[i]);        // q0 + i*q1
  }
  fwd_fft(buf, x, t);

  float2 z[4];
  #pragma unroll
  for (int m = 0; m < 4; ++m) {
    const int p   = t + 256 * m;
    const int bin = rev4(p);
    const int p2  = rev4((1024 - bin) & 1023);
    const float2 F1 = buf[pidx(p)], F2 = buf[pidx(p2)];
    const float q0r = 0.5f * (F1.x + F2.x), q0i = 0.5f * (F1.y - F2.y);
    const float q1r = 0.5f * (F1.y + F2.y), q1i = 0.5f * (F2.x - F1.x);
    const float2 m0 = mem0[p], m1 = mem1[p];
    // z = mem * conj(fq)
    const float z0r = m0.x * q0r + m0.y * q0i, z0i = m0.y * q0r - m0.x * q0i;
    const float z1r = m1.x * q1r + m1.y * q1i, z1i = m1.y * q1r - m1.x * q1i;
    z[m] = make_float2(z0r - z1i, z0i + z1r);    // z0 + i*z1
  }
  __syncthreads();                               // all buf reads complete
  #pragma unroll
  for (int m = 0; m < 4; ++m) buf[pidx(t + 256 * m)] = z[m];
  __syncthreads();
  #pragma unroll
  for (int n = 0; n < 4; ++n) x[n] = buf[pidx(4 * t + n)];

  inv_stage<1>(x, t);   xchg<1, 4>(buf, x, t);
  inv_stage<4>(x, t);   xchg<4, 16>(buf, x, t);
  inv_stage<16>(x, t);  xchg<16, 64>(buf, x, t);
  inv_stage<64>(x, t);  xchg<64, 256>(buf, x, t);
  inv_stage<256>(x, t);

  const float sc = 1.0f / 1024.0f;
  #pragma unroll
  for (int n = 0; n < 4; ++n) {
    const int i = t + 256 * n;
    row0[i] = x[n].x * sc;
    row1[i] = x[n].y * sc;
  }
}

// ---------------------------------------------------------------------------
extern "C" void kernel_launch(void* const* d_in, const int* in_sizes, int n_in,
                              void* d_out, int out_size, void* d_ws, size_t ws_size,
                              hipStream_t stream) {
  (void)in_sizes; (void)n_in; (void)out_size; (void)ws_size;
  const float* x  = (const float*)d_in[0];
  const float* Wq = (const float*)d_in[1];
  const float* Wk = (const float*)d_in[2];
  const float* Wv = (const float*)d_in[3];
  float* out = (float*)d_out;

  // ws layout (~27.8 MB; proven-safe budget ~34 MB)
  char* ws = (char*)d_ws;
  unsigned short* Wb = (unsigned short*)ws;
  unsigned short* xb = (unsigned short*)(ws + (size_t)3 * DD * DD * 2);
  float*          KV = (float*)(ws + (size_t)3 * DD * DD * 2 + (size_t)MQ * DD * 2);
  float2*       csum = (float2*)((char*)KV + (size_t)MQ * 2 * DD * 4);

  convert_w<<<dim3(DD * DD / 1024, 3), 256, 0, stream>>>(Wq, Wk, Wv, Wb);

  for (int b = 0; b < 4; ++b) {
    const float* xq   = x   + (size_t)b * MQ * DD;
    float*       outq = out + (size_t)b * MQ * DD;

    convert_bf16<<<MQ * DD / 1024, 256, 0, stream>>>(xq, xb);
    gemm_mfma<<<dim3(MQ / 128, DD / 128, 3), 256, 0, stream>>>(xb, Wb, outq, KV);
    bind_kernel<<<MQ, 256, 0, stream>>>(KV);
    scan_chunk_sum<<<dim3(CH, 4), 256, 0, stream>>>((const float2*)KV, csum);
    scan_chunk_scan<<<4, 256, 0, stream>>>(csum);
    scan_apply<<<dim3(CH, 4), 256, 0, stream>>>((float2*)KV, csum);
    unbind_kernel<<<MQ / 2, 256, 0, stream>>>(outq, (const float2*)KV);
  }
}

// Round 6
// 291.352 us; speedup vs baseline: 3.6281x; 1.2975x over previous
//
#include <hip/hip_runtime.h>

// Problem constants: B=4, S=2048, D=1024
#define BB 4
#define SS 2048
#define DD 1024
#define MH2 4096              // rows per half (2 batches); 2-pass pipeline, ws ~32 MB (< proven-safe 34.1 MB)
#define CH 64                 // scan chunks per batch
#define RR 32                 // rows per chunk (CH*RR = SS)
#define PI_F 3.14159265358979323846f

typedef __attribute__((ext_vector_type(8))) short bf16x8;
typedef __attribute__((ext_vector_type(4))) float f32x4;

// ---------------------------------------------------------------------------
// fp32 <-> bf16 helpers (RNE)
// ---------------------------------------------------------------------------
__device__ __forceinline__ unsigned short f2bf(float f) {
  unsigned int u = __float_as_uint(f);
  u = (u + 0x7FFFu + ((u >> 16) & 1u)) >> 16;
  return (unsigned short)u;
}
__device__ __forceinline__ float bf2f(unsigned short h) {
  return __uint_as_float(((unsigned int)h) << 16);
}

__global__ __launch_bounds__(256) void convert_bf16(
    const float* __restrict__ src, unsigned short* __restrict__ dst) {
  const long i = ((long)blockIdx.x * 256 + threadIdx.x) * 4;
  const float4 v = *(const float4*)&src[i];
  ushort4 o;
  o.x = f2bf(v.x); o.y = f2bf(v.y); o.z = f2bf(v.z); o.w = f2bf(v.w);
  *(ushort4*)&dst[i] = o;
}

__global__ __launch_bounds__(256) void convert_w(
    const float* __restrict__ Wq, const float* __restrict__ Wk,
    const float* __restrict__ Wv, unsigned short* __restrict__ dst) {
  const int z = blockIdx.y;
  const float* src = (z == 0) ? Wq : (z == 1) ? Wk : Wv;
  const long i = ((long)blockIdx.x * 256 + threadIdx.x) * 4;
  const float4 v = *(const float4*)&src[i];
  ushort4 o;
  o.x = f2bf(v.x); o.y = f2bf(v.y); o.z = f2bf(v.z); o.w = f2bf(v.w);
  *(ushort4*)&dst[(size_t)z * DD * DD + i] = o;
}

// ---------------------------------------------------------------------------
// MFMA GEMM (m97 structure). z=0: q fp32 -> outq (ldc=DD floats).
// z=1,2: k,v bf16 -> KV interleaved [row][k(1024)|v(1024)] ushort, ldc=2048.
// ---------------------------------------------------------------------------
__device__ __forceinline__ void async16(const void* g, void* l) {
  __builtin_amdgcn_global_load_lds(
      (const __attribute__((address_space(1))) void*)g,
      (__attribute__((address_space(3))) void*)l, 16, 0, 0);
}

__global__ __launch_bounds__(256) void gemm_mfma(
    const unsigned short* __restrict__ xb,
    const unsigned short* __restrict__ Wb,
    float* __restrict__ outq, unsigned short* __restrict__ KV) {
  const int z = blockIdx.z;
  const unsigned short* W = Wb + (size_t)z * DD * DD;

  __shared__ unsigned short Als[128 * 32];
  __shared__ unsigned short Bls[128 * 32];

  const int tid  = threadIdx.x;
  const int lane = tid & 63;
  const int wave = tid >> 6;
  const int wm = (wave & 1) * 64;
  const int wn = (wave >> 1) * 64;

  const long m0 = (long)blockIdx.x * 128;
  const long n0 = (long)blockIdx.y * 128;

  f32x4 acc[4][4] = {};

  for (int k0 = 0; k0 < DD; k0 += 32) {
    #pragma unroll
    for (int i = 0; i < 2; ++i) {
      const int slot = i * 256 + tid;
      const int row  = slot >> 2;
      const int kq   = slot & 3;
      async16(xb + (m0 + row) * DD + k0 + kq * 8, &Als[slot * 8]);
      async16(W  + (n0 + row) * DD + k0 + kq * 8, &Bls[slot * 8]);
    }
    __syncthreads();

    const int fr = lane & 15;
    const int kq = lane >> 4;
    bf16x8 af[4], bfr[4];
    #pragma unroll
    for (int mt = 0; mt < 4; ++mt)
      af[mt] = *(const bf16x8*)&Als[(wm + mt * 16 + fr) * 32 + kq * 8];
    #pragma unroll
    for (int nt = 0; nt < 4; ++nt)
      bfr[nt] = *(const bf16x8*)&Bls[(wn + nt * 16 + fr) * 32 + kq * 8];
    #pragma unroll
    for (int mt = 0; mt < 4; ++mt)
      #pragma unroll
      for (int nt = 0; nt < 4; ++nt)
        acc[mt][nt] = __builtin_amdgcn_mfma_f32_16x16x32_bf16(
            af[mt], bfr[nt], acc[mt][nt], 0, 0, 0);
    __syncthreads();
  }

  const int col = lane & 15;
  const int r0  = (lane >> 4) * 4;
  if (z == 0) {
    #pragma unroll
    for (int mt = 0; mt < 4; ++mt)
      #pragma unroll
      for (int nt = 0; nt < 4; ++nt)
        #pragma unroll
        for (int r = 0; r < 4; ++r) {
          const long m = m0 + wm + mt * 16 + r0 + r;
          const long n = n0 + wn + nt * 16 + col;
          outq[m * DD + n] = acc[mt][nt][r];
        }
  } else {
    unsigned short* Ck = KV + (size_t)(z - 1) * DD;
    #pragma unroll
    for (int mt = 0; mt < 4; ++mt)
      #pragma unroll
      for (int nt = 0; nt < 4; ++nt)
        #pragma unroll
        for (int r = 0; r < 4; ++r) {
          const long m = m0 + wm + mt * 16 + r0 + r;
          const long n = n0 + wn + nt * 16 + col;
          Ck[m * 2048 + n] = f2bf(acc[mt][nt][r]);
        }
  }
}

// ---------------------------------------------------------------------------
// Radix-4 FFT, N=1024, 256 threads, 4 complex/thread in registers (R5
// known-good). Forward DIF -> base-4 digit-reversed order; inverse DIT back.
// ---------------------------------------------------------------------------
__device__ __forceinline__ int pidx(int i) { return i + (i >> 6); }
#define BUFSZ 1040
__device__ __forceinline__ int pidx16(int i) { return i + (i >> 4); }
#define MEMSZ 546   // 513 slots + pads

__device__ __forceinline__ int rev4(int p) {
  unsigned r = __brev((unsigned)p) >> 22;
  return (int)(((r & 0x155u) << 1) | ((r & 0x2AAu) >> 1));
}

__host__ __device__ constexpr int clog2(int s) {
  return (s == 256) ? 8 : (s == 64) ? 6 : (s == 16) ? 4 : (s == 4) ? 2 : 0;
}

template <int S>
__device__ __forceinline__ void fwd_stage(float2 x[4], int t) {
  float c1 = 1.0f, s1 = 0.0f;
  if (S > 1) {
    const int j = t & (S - 1);
    __sincosf(-2.0f * PI_F * (float)j / (float)(4 * S), &s1, &c1);
  }
  const float c2 = c1 * c1 - s1 * s1, s2 = 2.0f * c1 * s1;
  const float c3 = c1 * c2 - s1 * s2, s3 = c1 * s2 + s1 * c2;
  const float Ar = x[0].x + x[2].x, Ai = x[0].y + x[2].y;
  const float Br = x[1].x + x[3].x, Bi = x[1].y + x[3].y;
  const float Cr = x[0].x - x[2].x, Ci = x[0].y - x[2].y;
  const float dr = x[1].x - x[3].x, di = x[1].y - x[3].y;
  const float y1r = Cr + di, y1i = Ci - dr;
  const float y2r = Ar - Br, y2i = Ai - Bi;
  const float y3r = Cr - di, y3i = Ci + dr;
  x[0] = make_float2(Ar + Br, Ai + Bi);
  x[1] = make_float2(y1r * c1 - y1i * s1, y1r * s1 + y1i * c1);
  x[2] = make_float2(y2r * c2 - y2i * s2, y2r * s2 + y2i * c2);
  x[3] = make_float2(y3r * c3 - y3i * s3, y3r * s3 + y3i * c3);
}

template <int S>
__device__ __forceinline__ void inv_stage(float2 x[4], int t) {
  float c1 = 1.0f, s1 = 0.0f;
  if (S > 1) {
    const int j = t & (S - 1);
    __sincosf(2.0f * PI_F * (float)j / (float)(4 * S), &s1, &c1);
  }
  const float c2 = c1 * c1 - s1 * s1, s2 = 2.0f * c1 * s1;
  const float c3 = c1 * c2 - s1 * s2, s3 = c1 * s2 + s1 * c2;
  const float u0r = x[0].x,                   u0i = x[0].y;
  const float u1r = x[1].x * c1 - x[1].y * s1, u1i = x[1].x * s1 + x[1].y * c1;
  const float u2r = x[2].x * c2 - x[2].y * s2, u2i = x[2].x * s2 + x[2].y * c2;
  const float u3r = x[3].x * c3 - x[3].y * s3, u3i = x[3].x * s3 + x[3].y * c3;
  const float Er = u0r + u2r, Ei = u0i + u2i;
  const float Fr = u0r - u2r, Fi = u0i - u2i;
  const float Gr = u1r + u3r, Gi = u1i + u3i;
  const float Hr = u1r - u3r, Hi = u1i - u3i;
  x[0] = make_float2(Er + Gr, Ei + Gi);
  x[1] = make_float2(Fr - Hi, Fi + Hr);
  x[2] = make_float2(Er - Gr, Ei - Gi);
  x[3] = make_float2(Fr + Hi, Fi - Hr);
}

template <int SW, int SR>
__device__ __forceinline__ void xchg(float2* buf, float2 x[4], int t) {
  constexpr int LW = clog2(SW), LR = clog2(SR);
  #pragma unroll
  for (int n = 0; n < 4; ++n)
    buf[pidx(((t >> LW) << (LW + 2)) + (t & (SW - 1)) + n * SW)] = x[n];
  __syncthreads();
  #pragma unroll
  for (int n = 0; n < 4; ++n)
    x[n] = buf[pidx(((t >> LR) << (LR + 2)) + (t & (SR - 1)) + n * SR)];
  __syncthreads();
}

__device__ __forceinline__ void fwd_fft(float2* buf, float2 x[4], int t) {
  fwd_stage<256>(x, t); xchg<256, 64>(buf, x, t);
  fwd_stage<64>(x, t);  xchg<64, 16>(buf, x, t);
  fwd_stage<16>(x, t);  xchg<16, 4>(buf, x, t);
  fwd_stage<4>(x, t);   xchg<4, 1>(buf, x, t);
  fwd_stage<1>(x, t);
  #pragma unroll
  for (int n = 0; n < 4; ++n) buf[pidx(4 * t + n)] = x[n];
  __syncthreads();
}

// ---------------------------------------------------------------------------
// Bind (in place): KV row [k|v] bf16 (4 KB) -> one FFT of k+iv, Hermitian
// split, P = fk*fv packed to HALF spectrum over the same 4 KB:
//   slot 0 = (P[0], P[512]) (both exactly real), slot s = P[s], s=1..511.
// P is Hermitian (product of Hermitian spectra), so this is lossless.
// ---------------------------------------------------------------------------
__global__ __launch_bounds__(256) void bind_kernel(unsigned short* __restrict__ KV) {
  __shared__ float2 buf[BUFSZ];
  const int t = threadIdx.x;
  unsigned short* row = KV + (long)blockIdx.x * 2048;

  float2 x[4];
  #pragma unroll
  for (int n = 0; n < 4; ++n) {
    const int i = t + 256 * n;
    x[n] = make_float2(bf2f(row[i]), bf2f(row[1024 + i]));   // k + i*v
  }
  fwd_fft(buf, x, t);

  float2* Prow = (float2*)row;   // 512 float2 = same 4 KB; all reads done
  #pragma unroll
  for (int m = 0; m < 2; ++m) {
    const int s = t + 256 * m;              // slot / natural bin, 0..511
    if (s == 0) {
      const float2 W0   = buf[pidx(0)];           // bin 0 (rev4(0)=0)
      const float2 W512 = buf[pidx(2)];           // bin 512 (rev4(512)=2)
      Prow[0] = make_float2(W0.x * W0.y, W512.x * W512.y);
    } else {
      const int p1 = rev4(s);
      const int p2 = rev4(1024 - s);
      const float2 F1 = buf[pidx(p1)], F2 = buf[pidx(p2)];
      const float fkr = 0.5f * (F1.x + F2.x), fki = 0.5f * (F1.y - F2.y);
      const float fvr = 0.5f * (F1.y + F2.y), fvi = 0.5f * (F2.x - F1.x);
      Prow[s] = make_float2(fkr * fvr - fki * fvi, fkr * fvi + fki * fvr);
    }
  }
}

// ---------------------------------------------------------------------------
// Causal cumsum over s per packed bin. P is contiguous: row r = 512 float2 at
// offset r*512. Componentwise float2 add is correct for slot 0 too (two reals).
// Grids cover 2 batches per half.
// ---------------------------------------------------------------------------
__global__ __launch_bounds__(256) void scan_chunk_sum(
    const float2* __restrict__ P, float2* __restrict__ csum) {
  const int chunk = blockIdx.x;                       // 0..63
  const int batch = blockIdx.y >> 1;                  // 0..1
  const int f = (blockIdx.y & 1) * 256 + threadIdx.x; // 0..511
  long base = ((long)batch * SS + (long)chunk * RR) * 512 + f;
  float sr = 0.0f, si = 0.0f;
  #pragma unroll 4
  for (int i = 0; i < RR; ++i) {
    float2 p = P[base + (long)i * 512];
    sr += p.x; si += p.y;
  }
  csum[((long)batch * CH + chunk) * 512 + f] = make_float2(sr, si);
}

__global__ __launch_bounds__(256) void scan_chunk_scan(float2* csum) {
  const int idx = blockIdx.x * 256 + threadIdx.x;  // 0..1023
  const int batch = idx >> 9;
  const int f = idx & 511;
  float2 v[CH];
  #pragma unroll
  for (int c = 0; c < CH; ++c) v[c] = csum[((long)batch * CH + c) * 512 + f];
  float rr = 0.0f, ri = 0.0f;
  #pragma unroll
  for (int c = 0; c < CH; ++c) {
    const float2 x = v[c];
    csum[((long)batch * CH + c) * 512 + f] = make_float2(rr, ri);
    rr += x.x; ri += x.y;
  }
}

__global__ __launch_bounds__(256) void scan_apply(
    float2* __restrict__ P, const float2* __restrict__ csum) {
  const int chunk = blockIdx.x;
  const int batch = blockIdx.y >> 1;
  const int f = (blockIdx.y & 1) * 256 + threadIdx.x;
  float2 off = csum[((long)batch * CH + chunk) * 512 + f];
  float ar = off.x, ai = off.y;
  long base = ((long)batch * SS + (long)chunk * RR) * 512 + f;
  for (int i = 0; i < RR; ++i) {
    const long o = base + (long)i * 512;
    float2 p = P[o];
    ar += p.x; ai += p.y;
    P[o] = make_float2(ar, ai);
  }
}

// ---------------------------------------------------------------------------
// Unbind, 2 rows/block (in place on d_out). mem rows are Hermitian-packed
// (512 float2); unpack into LDS slots 0..512, gather full spectrum with
// predicated conj for bins > 512. One fwd FFT (q0+iq1), one inv FFT (z0+iz1).
// ---------------------------------------------------------------------------
__global__ __launch_bounds__(256) void unbind_kernel(
    float* __restrict__ qout, const float2* __restrict__ mem) {
  __shared__ float2 buf[BUFSZ];
  __shared__ float2 m0s[MEMSZ], m1s[MEMSZ];
  const int t = threadIdx.x;
  const long r0 = (long)blockIdx.x * 2;
  float* row0 = qout + r0 * DD;
  float* row1 = row0 + DD;
  const float2* mem0 = mem + r0 * 512;
  const float2* mem1 = mem0 + 512;

  // load q rows + unpack mem rows into LDS (slots 0..512, natural bins)
  float2 x[4];
  #pragma unroll
  for (int n = 0; n < 4; ++n) {
    const int i = t + 256 * n;
    x[n] = make_float2(row0[i], row1[i]);        // q0 + i*q1
  }
  #pragma unroll
  for (int n = 0; n < 2; ++n) {
    const int s = t + 256 * n;                   // 0..511
    const float2 a = mem0[s], b = mem1[s];
    if (s == 0) {
      m0s[pidx16(0)]   = make_float2(a.x, 0.0f);
      m0s[pidx16(512)] = make_float2(a.y, 0.0f);
      m1s[pidx16(0)]   = make_float2(b.x, 0.0f);
      m1s[pidx16(512)] = make_float2(b.y, 0.0f);
    } else {
      m0s[pidx16(s)] = a;
      m1s[pidx16(s)] = b;
    }
  }
  // fwd_fft's internal barriers order these LDS writes before the gathers
  fwd_fft(buf, x, t);

  float2 z[4];
  #pragma unroll
  for (int m = 0; m < 4; ++m) {
    const int p   = t + 256 * m;
    const int bin = rev4(p);
    const int p2  = rev4((1024 - bin) & 1023);
    const float2 F1 = buf[pidx(p)], F2 = buf[pidx(p2)];
    const float q0r = 0.5f * (F1.x + F2.x), q0i = 0.5f * (F1.y - F2.y);
    const float q1r = 0.5f * (F1.y + F2.y), q1i = 0.5f * (F2.x - F1.x);
    const int  ix = (bin <= 512) ? bin : 1024 - bin;
    const float sg = (bin <= 512) ? 1.0f : -1.0f;
    float2 m0 = m0s[pidx16(ix)], m1 = m1s[pidx16(ix)];
    m0.y *= sg; m1.y *= sg;
    const float z0r = m0.x * q0r + m0.y * q0i, z0i = m0.y * q0r - m0.x * q0i;
    const float z1r = m1.x * q1r + m1.y * q1i, z1i = m1.y * q1r - m1.x * q1i;
    z[m] = make_float2(z0r - z1i, z0i + z1r);    // z0 + i*z1
  }
  __syncthreads();
  #pragma unroll
  for (int m = 0; m < 4; ++m) buf[pidx(t + 256 * m)] = z[m];
  __syncthreads();
  #pragma unroll
  for (int n = 0; n < 4; ++n) x[n] = buf[pidx(4 * t + n)];

  inv_stage<1>(x, t);   xchg<1, 4>(buf, x, t);
  inv_stage<4>(x, t);   xchg<4, 16>(buf, x, t);
  inv_stage<16>(x, t);  xchg<16, 64>(buf, x, t);
  inv_stage<64>(x, t);  xchg<64, 256>(buf, x, t);
  inv_stage<256>(x, t);

  const float sc = 1.0f / 1024.0f;
  #pragma unroll
  for (int n = 0; n < 4; ++n) {
    const int i = t + 256 * n;
    row0[i] = x[n].x * sc;
    row1[i] = x[n].y * sc;
  }
}

// ---------------------------------------------------------------------------
extern "C" void kernel_launch(void* const* d_in, const int* in_sizes, int n_in,
                              void* d_out, int out_size, void* d_ws, size_t ws_size,
                              hipStream_t stream) {
  (void)in_sizes; (void)n_in; (void)out_size; (void)ws_size;
  const float* x  = (const float*)d_in[0];
  const float* Wq = (const float*)d_in[1];
  const float* Wk = (const float*)d_in[2];
  const float* Wv = (const float*)d_in[3];
  float* out = (float*)d_out;

  // ws layout (32.0 MB total; proven-safe budget 34.1 MB):
  //   Wb  : 3*1024*1024 bf16      = 6.29 MB
  //   xb  : 4096*1024 bf16        = 8.39 MB   (half's x)
  //   KV/P: 4096 rows * 4 KB      = 16.78 MB  (bf16 k|v, then packed P in place)
  //   csum: 2*64*512 float2       = 0.52 MB
  char* ws = (char*)d_ws;
  unsigned short* Wb = (unsigned short*)ws;
  unsigned short* xb = (unsigned short*)(ws + (size_t)3 * DD * DD * 2);
  unsigned short* KV = (unsigned short*)(ws + (size_t)3 * DD * DD * 2 +
                                         (size_t)MH2 * DD * 2);
  float2*       csum = (float2*)((char*)KV + (size_t)MH2 * 2048 * 2);

  convert_w<<<dim3(DD * DD / 1024, 3), 256, 0, stream>>>(Wq, Wk, Wv, Wb);

  for (int h = 0; h < 2; ++h) {
    const float* xh   = x   + (size_t)h * MH2 * DD;
    float*       outh = out + (size_t)h * MH2 * DD;

    convert_bf16<<<MH2 * DD / 1024, 256, 0, stream>>>(xh, xb);
    gemm_mfma<<<dim3(MH2 / 128, DD / 128, 3), 256, 0, stream>>>(xb, Wb, outh, KV);
    bind_kernel<<<MH2, 256, 0, stream>>>(KV);
    scan_chunk_sum<<<dim3(CH, 4), 256, 0, stream>>>((const float2*)KV, csum);
    scan_chunk_scan<<<4, 256, 0, stream>>>(csum);
    scan_apply<<<dim3(CH, 4), 256, 0, stream>>>((float2*)KV, csum);
    unbind_kernel<<<MH2 / 2, 256, 0, stream>>>(outh, (const float2*)KV);
  }
}

// Round 7
// 234.161 us; speedup vs baseline: 4.5142x; 1.2442x over previous
//
#include <hip/hip_runtime.h>

// Problem constants: B=4, S=2048, D=1024
#define BB 4
#define SS 2048
#define DD 1024
#define MM 8192               // total rows
#define CH 64                 // scan chunks per batch
#define RR 32                 // rows per chunk (CH*RR = SS)
#define PI_F 3.14159265358979323846f

typedef __attribute__((ext_vector_type(8))) short bf16x8;
typedef __attribute__((ext_vector_type(4))) float f32x4;

// ---------------------------------------------------------------------------
// fp32 <-> bf16 helpers (RNE)
// ---------------------------------------------------------------------------
__device__ __forceinline__ unsigned short f2bf(float f) {
  unsigned int u = __float_as_uint(f);
  u = (u + 0x7FFFu + ((u >> 16) & 1u)) >> 16;
  return (unsigned short)u;
}
__device__ __forceinline__ float bf2f(unsigned short h) {
  return __uint_as_float(((unsigned int)h) << 16);
}

__global__ __launch_bounds__(256) void convert_bf16(
    const float* __restrict__ src, unsigned short* __restrict__ dst) {
  const long i = ((long)blockIdx.x * 256 + threadIdx.x) * 4;
  const float4 v = *(const float4*)&src[i];
  ushort4 o;
  o.x = f2bf(v.x); o.y = f2bf(v.y); o.z = f2bf(v.z); o.w = f2bf(v.w);
  *(ushort4*)&dst[i] = o;
}

__global__ __launch_bounds__(256) void convert_w(
    const float* __restrict__ Wq, const float* __restrict__ Wk,
    const float* __restrict__ Wv, unsigned short* __restrict__ dst) {
  const int z = blockIdx.y;
  const float* src = (z == 0) ? Wq : (z == 1) ? Wk : Wv;
  const long i = ((long)blockIdx.x * 256 + threadIdx.x) * 4;
  const float4 v = *(const float4*)&src[i];
  ushort4 o;
  o.x = f2bf(v.x); o.y = f2bf(v.y); o.z = f2bf(v.z); o.w = f2bf(v.w);
  *(ushort4*)&dst[(size_t)z * DD * DD + i] = o;
}

// ---------------------------------------------------------------------------
// MFMA GEMM, BK=64 (16 K-iters -> half the barrier drains of R6's BK=32).
// XOR swizzle on staged 16B quads (g = kq ^ (row&7)) keeps ds_read conflicts
// at the BK=32 level; legal because the permutation preserves the
// wave-contiguous lane*16B LDS mapping global_load_lds requires (m104/m108).
// z=0: q fp32 -> outq. z=1,2: k,v bf16 -> KV interleaved [row][k|v], ld 2048.
// ---------------------------------------------------------------------------
__device__ __forceinline__ void async16(const void* g, void* l) {
  __builtin_amdgcn_global_load_lds(
      (const __attribute__((address_space(1))) void*)g,
      (__attribute__((address_space(3))) void*)l, 16, 0, 0);
}

__global__ __launch_bounds__(256) void gemm_mfma(
    const unsigned short* __restrict__ xb,
    const unsigned short* __restrict__ Wb,
    float* __restrict__ outq, unsigned short* __restrict__ KV) {
  const int z = blockIdx.z;
  const unsigned short* W = Wb + (size_t)z * DD * DD;

  __shared__ unsigned short Als[128 * 64];   // 16 KB
  __shared__ unsigned short Bls[128 * 64];   // 16 KB

  const int tid  = threadIdx.x;
  const int lane = tid & 63;
  const int wave = tid >> 6;
  const int wm = (wave & 1) * 64;
  const int wn = (wave >> 1) * 64;

  const long m0 = (long)blockIdx.x * 128;
  const long n0 = (long)blockIdx.y * 128;

  f32x4 acc[4][4] = {};

  for (int k0 = 0; k0 < DD; k0 += 64) {
    // 1024 slots x 16B per tile; slot -> (row = slot>>3, quad kq = slot&7)
    #pragma unroll
    for (int i = 0; i < 4; ++i) {
      const int slot = i * 256 + tid;
      const int row  = slot >> 3;
      const int kq   = slot & 7;
      const int g    = kq ^ (row & 7);     // swizzled source quad
      async16(xb + (m0 + row) * DD + k0 + g * 8, &Als[slot * 8]);
      async16(W  + (n0 + row) * DD + k0 + g * 8, &Bls[slot * 8]);
    }
    __syncthreads();

    const int fr = lane & 15;
    const int kq = lane >> 4;
    #pragma unroll
    for (int h = 0; h < 2; ++h) {          // two 32-wide k-chunks
      bf16x8 af[4], bfr[4];
      #pragma unroll
      for (int mt = 0; mt < 4; ++mt) {
        const int row = wm + mt * 16 + fr;
        af[mt] = *(const bf16x8*)
            &Als[row * 64 + ((((h << 2) + kq) ^ (fr & 7)) << 3)];
      }
      #pragma unroll
      for (int nt = 0; nt < 4; ++nt) {
        const int row = wn + nt * 16 + fr;
        bfr[nt] = *(const bf16x8*)
            &Bls[row * 64 + ((((h << 2) + kq) ^ (fr & 7)) << 3)];
      }
      #pragma unroll
      for (int mt = 0; mt < 4; ++mt)
        #pragma unroll
        for (int nt = 0; nt < 4; ++nt)
          acc[mt][nt] = __builtin_amdgcn_mfma_f32_16x16x32_bf16(
              af[mt], bfr[nt], acc[mt][nt], 0, 0, 0);
    }
    __syncthreads();
  }

  const int col = lane & 15;
  const int r0  = (lane >> 4) * 4;
  if (z == 0) {
    #pragma unroll
    for (int mt = 0; mt < 4; ++mt)
      #pragma unroll
      for (int nt = 0; nt < 4; ++nt)
        #pragma unroll
        for (int r = 0; r < 4; ++r) {
          const long m = m0 + wm + mt * 16 + r0 + r;
          const long n = n0 + wn + nt * 16 + col;
          outq[m * DD + n] = acc[mt][nt][r];
        }
  } else {
    unsigned short* Ck = KV + (size_t)(z - 1) * DD;
    #pragma unroll
    for (int mt = 0; mt < 4; ++mt)
      #pragma unroll
      for (int nt = 0; nt < 4; ++nt)
        #pragma unroll
        for (int r = 0; r < 4; ++r) {
          const long m = m0 + wm + mt * 16 + r0 + r;
          const long n = n0 + wn + nt * 16 + col;
          Ck[m * 2048 + n] = f2bf(acc[mt][nt][r]);
        }
  }
}

// ---------------------------------------------------------------------------
// Radix-4 FFT, N=1024, 256 threads, 4 complex/thread in registers (R5/R6
// known-good). Forward DIF -> base-4 digit-reversed order; inverse DIT back.
// ---------------------------------------------------------------------------
__device__ __forceinline__ int pidx(int i) { return i + (i >> 6); }
#define BUFSZ 1040
__device__ __forceinline__ int pidx16(int i) { return i + (i >> 4); }
#define MEMSZ 546   // 513 slots + pads

__device__ __forceinline__ int rev4(int p) {
  unsigned r = __brev((unsigned)p) >> 22;
  return (int)(((r & 0x155u) << 1) | ((r & 0x2AAu) >> 1));
}

__host__ __device__ constexpr int clog2(int s) {
  return (s == 256) ? 8 : (s == 64) ? 6 : (s == 16) ? 4 : (s == 4) ? 2 : 0;
}

template <int S>
__device__ __forceinline__ void fwd_stage(float2 x[4], int t) {
  float c1 = 1.0f, s1 = 0.0f;
  if (S > 1) {
    const int j = t & (S - 1);
    __sincosf(-2.0f * PI_F * (float)j / (float)(4 * S), &s1, &c1);
  }
  const float c2 = c1 * c1 - s1 * s1, s2 = 2.0f * c1 * s1;
  const float c3 = c1 * c2 - s1 * s2, s3 = c1 * s2 + s1 * c2;
  const float Ar = x[0].x + x[2].x, Ai = x[0].y + x[2].y;
  const float Br = x[1].x + x[3].x, Bi = x[1].y + x[3].y;
  const float Cr = x[0].x - x[2].x, Ci = x[0].y - x[2].y;
  const float dr = x[1].x - x[3].x, di = x[1].y - x[3].y;
  const float y1r = Cr + di, y1i = Ci - dr;
  const float y2r = Ar - Br, y2i = Ai - Bi;
  const float y3r = Cr - di, y3i = Ci + dr;
  x[0] = make_float2(Ar + Br, Ai + Bi);
  x[1] = make_float2(y1r * c1 - y1i * s1, y1r * s1 + y1i * c1);
  x[2] = make_float2(y2r * c2 - y2i * s2, y2r * s2 + y2i * c2);
  x[3] = make_float2(y3r * c3 - y3i * s3, y3r * s3 + y3i * c3);
}

template <int S>
__device__ __forceinline__ void inv_stage(float2 x[4], int t) {
  float c1 = 1.0f, s1 = 0.0f;
  if (S > 1) {
    const int j = t & (S - 1);
    __sincosf(2.0f * PI_F * (float)j / (float)(4 * S), &s1, &c1);
  }
  const float c2 = c1 * c1 - s1 * s1, s2 = 2.0f * c1 * s1;
  const float c3 = c1 * c2 - s1 * s2, s3 = c1 * s2 + s1 * c2;
  const float u0r = x[0].x,                   u0i = x[0].y;
  const float u1r = x[1].x * c1 - x[1].y * s1, u1i = x[1].x * s1 + x[1].y * c1;
  const float u2r = x[2].x * c2 - x[2].y * s2, u2i = x[2].x * s2 + x[2].y * c2;
  const float u3r = x[3].x * c3 - x[3].y * s3, u3i = x[3].x * s3 + x[3].y * c3;
  const float Er = u0r + u2r, Ei = u0i + u2i;
  const float Fr = u0r - u2r, Fi = u0i - u2i;
  const float Gr = u1r + u3r, Gi = u1i + u3i;
  const float Hr = u1r - u3r, Hi = u1i - u3i;
  x[0] = make_float2(Er + Gr, Ei + Gi);
  x[1] = make_float2(Fr - Hi, Fi + Hr);
  x[2] = make_float2(Er - Gr, Ei - Gi);
  x[3] = make_float2(Fr + Hi, Fi - Hr);
}

template <int SW, int SR>
__device__ __forceinline__ void xchg(float2* buf, float2 x[4], int t) {
  constexpr int LW = clog2(SW), LR = clog2(SR);
  #pragma unroll
  for (int n = 0; n < 4; ++n)
    buf[pidx(((t >> LW) << (LW + 2)) + (t & (SW - 1)) + n * SW)] = x[n];
  __syncthreads();
  #pragma unroll
  for (int n = 0; n < 4; ++n)
    x[n] = buf[pidx(((t >> LR) << (LR + 2)) + (t & (SR - 1)) + n * SR)];
  __syncthreads();
}

__device__ __forceinline__ void fwd_fft(float2* buf, float2 x[4], int t) {
  fwd_stage<256>(x, t); xchg<256, 64>(buf, x, t);
  fwd_stage<64>(x, t);  xchg<64, 16>(buf, x, t);
  fwd_stage<16>(x, t);  xchg<16, 4>(buf, x, t);
  fwd_stage<4>(x, t);   xchg<4, 1>(buf, x, t);
  fwd_stage<1>(x, t);
  #pragma unroll
  for (int n = 0; n < 4; ++n) buf[pidx(4 * t + n)] = x[n];
  __syncthreads();
}

// ---------------------------------------------------------------------------
// Bind (in place): KV row [k|v] bf16 (4 KB) -> one FFT of k+iv, Hermitian
// split, P = fk*fv packed to HALF spectrum over the same 4 KB:
//   slot 0 = (P[0], P[512]) (both exactly real), slot s = P[s], s=1..511.
// ---------------------------------------------------------------------------
__global__ __launch_bounds__(256) void bind_kernel(unsigned short* __restrict__ KV) {
  __shared__ float2 buf[BUFSZ];
  const int t = threadIdx.x;
  unsigned short* row = KV + (long)blockIdx.x * 2048;

  float2 x[4];
  #pragma unroll
  for (int n = 0; n < 4; ++n) {
    const int i = t + 256 * n;
    x[n] = make_float2(bf2f(row[i]), bf2f(row[1024 + i]));   // k + i*v
  }
  fwd_fft(buf, x, t);

  float2* Prow = (float2*)row;
  #pragma unroll
  for (int m = 0; m < 2; ++m) {
    const int s = t + 256 * m;
    if (s == 0) {
      const float2 W0   = buf[pidx(0)];
      const float2 W512 = buf[pidx(2)];
      Prow[0] = make_float2(W0.x * W0.y, W512.x * W512.y);
    } else {
      const int p1 = rev4(s);
      const int p2 = rev4(1024 - s);
      const float2 F1 = buf[pidx(p1)], F2 = buf[pidx(p2)];
      const float fkr = 0.5f * (F1.x + F2.x), fki = 0.5f * (F1.y - F2.y);
      const float fvr = 0.5f * (F1.y + F2.y), fvi = 0.5f * (F2.x - F1.x);
      Prow[s] = make_float2(fkr * fvr - fki * fvi, fkr * fvi + fki * fvr);
    }
  }
}

// ---------------------------------------------------------------------------
// Causal cumsum over s per packed bin; grids cover nB batches (gridDim.y=2*nB).
// ---------------------------------------------------------------------------
__global__ __launch_bounds__(256) void scan_chunk_sum(
    const float2* __restrict__ P, float2* __restrict__ csum) {
  const int chunk = blockIdx.x;
  const int batch = blockIdx.y >> 1;
  const int f = (blockIdx.y & 1) * 256 + threadIdx.x;
  long base = ((long)batch * SS + (long)chunk * RR) * 512 + f;
  float sr = 0.0f, si = 0.0f;
  #pragma unroll 4
  for (int i = 0; i < RR; ++i) {
    float2 p = P[base + (long)i * 512];
    sr += p.x; si += p.y;
  }
  csum[((long)batch * CH + chunk) * 512 + f] = make_float2(sr, si);
}

__global__ __launch_bounds__(256) void scan_chunk_scan(float2* csum) {
  const int idx = blockIdx.x * 256 + threadIdx.x;
  const int batch = idx >> 9;
  const int f = idx & 511;
  float2 v[CH];
  #pragma unroll
  for (int c = 0; c < CH; ++c) v[c] = csum[((long)batch * CH + c) * 512 + f];
  float rr = 0.0f, ri = 0.0f;
  #pragma unroll
  for (int c = 0; c < CH; ++c) {
    const float2 x = v[c];
    csum[((long)batch * CH + c) * 512 + f] = make_float2(rr, ri);
    rr += x.x; ri += x.y;
  }
}

__global__ __launch_bounds__(256) void scan_apply(
    float2* __restrict__ P, const float2* __restrict__ csum) {
  const int chunk = blockIdx.x;
  const int batch = blockIdx.y >> 1;
  const int f = (blockIdx.y & 1) * 256 + threadIdx.x;
  float2 off = csum[((long)batch * CH + chunk) * 512 + f];
  float ar = off.x, ai = off.y;
  long base = ((long)batch * SS + (long)chunk * RR) * 512 + f;
  for (int i = 0; i < RR; ++i) {
    const long o = base + (long)i * 512;
    float2 p = P[o];
    ar += p.x; ai += p.y;
    P[o] = make_float2(ar, ai);
  }
}

// ---------------------------------------------------------------------------
// Unbind, 2 rows/block (in place on d_out). mem rows Hermitian-packed;
// unpack into LDS, gather with predicated conj; one fwd FFT (q0+iq1),
// one inv FFT (z0+iz1).
// ---------------------------------------------------------------------------
__global__ __launch_bounds__(256) void unbind_kernel(
    float* __restrict__ qout, const float2* __restrict__ mem) {
  __shared__ float2 buf[BUFSZ];
  __shared__ float2 m0s[MEMSZ], m1s[MEMSZ];
  const int t = threadIdx.x;
  const long r0 = (long)blockIdx.x * 2;
  float* row0 = qout + r0 * DD;
  float* row1 = row0 + DD;
  const float2* mem0 = mem + r0 * 512;
  const float2* mem1 = mem0 + 512;

  float2 x[4];
  #pragma unroll
  for (int n = 0; n < 4; ++n) {
    const int i = t + 256 * n;
    x[n] = make_float2(row0[i], row1[i]);        // q0 + i*q1
  }
  #pragma unroll
  for (int n = 0; n < 2; ++n) {
    const int s = t + 256 * n;
    const float2 a = mem0[s], b = mem1[s];
    if (s == 0) {
      m0s[pidx16(0)]   = make_float2(a.x, 0.0f);
      m0s[pidx16(512)] = make_float2(a.y, 0.0f);
      m1s[pidx16(0)]   = make_float2(b.x, 0.0f);
      m1s[pidx16(512)] = make_float2(b.y, 0.0f);
    } else {
      m0s[pidx16(s)] = a;
      m1s[pidx16(s)] = b;
    }
  }
  fwd_fft(buf, x, t);   // internal barriers order the m*s writes too

  float2 z[4];
  #pragma unroll
  for (int m = 0; m < 4; ++m) {
    const int p   = t + 256 * m;
    const int bin = rev4(p);
    const int p2  = rev4((1024 - bin) & 1023);
    const float2 F1 = buf[pidx(p)], F2 = buf[pidx(p2)];
    const float q0r = 0.5f * (F1.x + F2.x), q0i = 0.5f * (F1.y - F2.y);
    const float q1r = 0.5f * (F1.y + F2.y), q1i = 0.5f * (F2.x - F1.x);
    const int  ix = (bin <= 512) ? bin : 1024 - bin;
    const float sg = (bin <= 512) ? 1.0f : -1.0f;
    float2 m0 = m0s[pidx16(ix)], m1 = m1s[pidx16(ix)];
    m0.y *= sg; m1.y *= sg;
    const float z0r = m0.x * q0r + m0.y * q0i, z0i = m0.y * q0r - m0.x * q0i;
    const float z1r = m1.x * q1r + m1.y * q1i, z1i = m1.y * q1r - m1.x * q1i;
    z[m] = make_float2(z0r - z1i, z0i + z1r);    // z0 + i*z1
  }
  __syncthreads();
  #pragma unroll
  for (int m = 0; m < 4; ++m) buf[pidx(t + 256 * m)] = z[m];
  __syncthreads();
  #pragma unroll
  for (int n = 0; n < 4; ++n) x[n] = buf[pidx(4 * t + n)];

  inv_stage<1>(x, t);   xchg<1, 4>(buf, x, t);
  inv_stage<4>(x, t);   xchg<4, 16>(buf, x, t);
  inv_stage<16>(x, t);  xchg<16, 64>(buf, x, t);
  inv_stage<64>(x, t);  xchg<64, 256>(buf, x, t);
  inv_stage<256>(x, t);

  const float sc = 1.0f / 1024.0f;
  #pragma unroll
  for (int n = 0; n < 4; ++n) {
    const int i = t + 256 * n;
    row0[i] = x[n].x * sc;
    row1[i] = x[n].y * sc;
  }
}

// ---------------------------------------------------------------------------
extern "C" void kernel_launch(void* const* d_in, const int* in_sizes, int n_in,
                              void* d_out, int out_size, void* d_ws, size_t ws_size,
                              hipStream_t stream) {
  (void)in_sizes; (void)n_in; (void)out_size;
  const float* x  = (const float*)d_in[0];
  const float* Wq = (const float*)d_in[1];
  const float* Wk = (const float*)d_in[2];
  const float* Wv = (const float*)d_in[3];
  float* out = (float*)d_out;

  // ws layout for MH rows/pass, nB batches/pass:
  //   Wb   : 3*1024*1024 bf16       = 6.29 MB
  //   xb   : MH*1024 bf16
  //   KV/P : MH rows * 4 KB
  //   csum : nB*64*512 float2
  // Single-pass (MH=8192): 57.67 MB; two-pass (MH=4096): 32.0 MB (proven-safe
  // budget is 34.1 MB; ws_size known >= that from R2). Branch on ws_size —
  // constant across calls, so graph-safe.
  const size_t wbytes = (size_t)3 * DD * DD * 2;
  auto need = [&](size_t MHr, size_t nB) {
    return wbytes + MHr * DD * 2 + MHr * 4096 + nB * CH * 512 * 8;
  };
  const int nPass = (ws_size >= need(8192, 4)) ? 1 : 2;
  const size_t MH = MM / nPass;          // rows per pass
  const int    nB = BB / nPass;          // batches per pass

  char* ws = (char*)d_ws;
  unsigned short* Wb = (unsigned short*)ws;
  unsigned short* xb = (unsigned short*)(ws + wbytes);
  unsigned short* KV = (unsigned short*)(ws + wbytes + MH * DD * 2);
  float2*       csum = (float2*)((char*)KV + MH * 4096);

  convert_w<<<dim3(DD * DD / 1024, 3), 256, 0, stream>>>(Wq, Wk, Wv, Wb);

  for (int h = 0; h < nPass; ++h) {
    const float* xh   = x   + (size_t)h * MH * DD;
    float*       outh = out + (size_t)h * MH * DD;

    convert_bf16<<<MH * DD / 1024, 256, 0, stream>>>(xh, xb);
    gemm_mfma<<<dim3(MH / 128, DD / 128, 3), 256, 0, stream>>>(xb, Wb, outh, KV);
    bind_kernel<<<MH, 256, 0, stream>>>(KV);
    scan_chunk_sum<<<dim3(CH, nB * 2), 256, 0, stream>>>((const float2*)KV, csum);
    scan_chunk_scan<<<nB * 2, 256, 0, stream>>>(csum);
    scan_apply<<<dim3(CH, nB * 2), 256, 0, stream>>>((float2*)KV, csum);
    unbind_kernel<<<MH / 2, 256, 0, stream>>>(outh, (const float2*)KV);
  }
}